// Round 3
// baseline (5063.831 us; speedup 1.0000x reference)
//
#include <hip/hip_runtime.h>
#include <hip/hip_bf16.h>

#define B 2
#define S 2048
#define D 1024
#define NH 16
#define DH 64
#define M (B*S)

// ---------- GEMM: Out[m,n] = sum_k X[m,k]*W[k,n]; fp32 in/out
__global__ __launch_bounds__(256) void gemm_qkv(const float* __restrict__ X,
                                                const float* __restrict__ W,
                                                float* __restrict__ Out) {
    __shared__ float Xs[32][33];
    __shared__ float Ws[32][33];
    const int tx = threadIdx.x;          // 0..31
    const int ty = threadIdx.y;          // 0..7
    const int row0 = blockIdx.y * 32;
    const int col0 = blockIdx.x * 32;
    float acc[4] = {0.f, 0.f, 0.f, 0.f};
    for (int k0 = 0; k0 < D; k0 += 32) {
#pragma unroll
        for (int i = 0; i < 4; i++) {
            int r = ty + 8 * i;
            Xs[r][tx] = X[(size_t)(row0 + r) * D + k0 + tx];
            Ws[r][tx] = W[(size_t)(k0 + r) * D + col0 + tx];
        }
        __syncthreads();
#pragma unroll
        for (int kk = 0; kk < 32; kk++) {
            float w = Ws[kk][tx];
#pragma unroll
            for (int i = 0; i < 4; i++) acc[i] += Xs[ty * 4 + i][kk] * w;
        }
        __syncthreads();
    }
#pragma unroll
    for (int i = 0; i < 4; i++)
        Out[(size_t)(row0 + ty * 4 + i) * D + col0 + tx] = acc[i];
}

// ---------- Output projection: Out = Ctx @ Wo + bo, fp32 everywhere
__global__ __launch_bounds__(256) void gemm_out(const float* __restrict__ X,
                                                const float* __restrict__ W,
                                                const float* __restrict__ bias,
                                                float* __restrict__ Out) {
    __shared__ float Xs[32][33];
    __shared__ float Ws[32][33];
    const int tx = threadIdx.x;
    const int ty = threadIdx.y;
    const int row0 = blockIdx.y * 32;
    const int col0 = blockIdx.x * 32;
    float acc[4] = {0.f, 0.f, 0.f, 0.f};
    for (int k0 = 0; k0 < D; k0 += 32) {
#pragma unroll
        for (int i = 0; i < 4; i++) {
            int r = ty + 8 * i;
            Xs[r][tx] = X[(size_t)(row0 + r) * D + k0 + tx];
            Ws[r][tx] = W[(size_t)(k0 + r) * D + col0 + tx];
        }
        __syncthreads();
#pragma unroll
        for (int kk = 0; kk < 32; kk++) {
            float w = Ws[kk][tx];
#pragma unroll
            for (int i = 0; i < 4; i++) acc[i] += Xs[ty * 4 + i][kk] * w;
        }
        __syncthreads();
    }
    const float bv = bias[col0 + tx];
#pragma unroll
    for (int i = 0; i < 4; i++)
        Out[(size_t)(row0 + ty * 4 + i) * D + col0 + tx] = acc[i] + bv;
}

// ---------- Causal attention, one block per (query row, b*h)
// Q/K/V layout: [B,S,D] with head h at columns h*DH..h*DH+63.
// Ctx may ALIAS Q: each block reads only Q[qi, h-block] (its own) before
// writing Ctx[qi, h-block] — disjoint across blocks.
__global__ __launch_bounds__(256) void attn_kernel(const float* __restrict__ Q,
                                                   const float* __restrict__ K,
                                                   const float* __restrict__ V,
                                                   float* __restrict__ Ctx) {
    const int qi  = blockIdx.x;
    const int bh  = blockIdx.y;
    const int b   = bh >> 4;
    const int h   = bh & 15;
    const int tid = threadIdx.x;

    __shared__ float kv[128 * 65];   // staged K or V tile, +1 stride padding
    __shared__ float sc[S];          // scores -> probabilities
    __shared__ float qs[DH];
    __shared__ float red[4];
    __shared__ float pacc[256];

    const size_t base = (size_t)b * S * D + (size_t)h * DH;
    if (tid < DH) qs[tid] = Q[base + (size_t)qi * D + tid];
    const int nk = qi + 1;

    // ---- pass 1: scores = (q . k) / sqrt(DH) for k in [0, qi]
    for (int k0 = 0; k0 < nk; k0 += 128) {
        const int kt = min(128, nk - k0);
        __syncthreads();
        for (int i = tid; i < kt * DH; i += 256) {
            int kr = i >> 6, dd = i & 63;
            kv[kr * 65 + dd] = K[base + (size_t)(k0 + kr) * D + dd];
        }
        __syncthreads();
        for (int kk = tid; kk < kt; kk += 256) {
            const float* kp = &kv[kk * 65];
            float s = 0.f;
#pragma unroll
            for (int dd = 0; dd < DH; dd++) s += qs[dd] * kp[dd];
            sc[k0 + kk] = s * 0.125f;   // 1/sqrt(64)
        }
    }
    __syncthreads();

    // ---- softmax max
    float m = -3.0e38f;
    for (int i = tid; i < nk; i += 256) m = fmaxf(m, sc[i]);
#pragma unroll
    for (int o = 32; o > 0; o >>= 1) m = fmaxf(m, __shfl_down(m, o, 64));
    if ((tid & 63) == 0) red[tid >> 6] = m;
    __syncthreads();
    m = fmaxf(fmaxf(red[0], red[1]), fmaxf(red[2], red[3]));
    __syncthreads();

    // ---- exp + sum
    float lsum = 0.f;
    for (int i = tid; i < nk; i += 256) {
        float e = __expf(sc[i] - m);
        sc[i] = e;
        lsum += e;
    }
#pragma unroll
    for (int o = 32; o > 0; o >>= 1) lsum += __shfl_down(lsum, o, 64);
    if ((tid & 63) == 0) red[tid >> 6] = lsum;
    __syncthreads();
    const float inv = 1.f / (red[0] + red[1] + red[2] + red[3]);

    // ---- PV: thread owns dim d = tid&63, key-subset part = tid>>6
    const int d = tid & 63, part = tid >> 6;
    float acc = 0.f;
    for (int k0 = 0; k0 < nk; k0 += 128) {
        const int kt = min(128, nk - k0);
        __syncthreads();
        for (int i = tid; i < kt * DH; i += 256) {
            int kr = i >> 6, dd = i & 63;
            kv[kr * 65 + dd] = V[base + (size_t)(k0 + kr) * D + dd];
        }
        __syncthreads();
        for (int kk = part; kk < kt; kk += 4) acc += sc[k0 + kk] * kv[kk * 65 + d];
    }
    pacc[tid] = acc;
    __syncthreads();
    if (tid < DH) {
        float r = (pacc[tid] + pacc[64 + tid] + pacc[128 + tid] + pacc[192 + tid]) * inv;
        Ctx[base + (size_t)qi * D + tid] = r;
    }
}

extern "C" void kernel_launch(void* const* d_in, const int* in_sizes, int n_in,
                              void* d_out, int out_size, void* d_ws, size_t ws_size,
                              hipStream_t stream) {
    const float* x  = (const float*)d_in[0];
    const float* Wq = (const float*)d_in[1];
    const float* Wk = (const float*)d_in[2];
    const float* Wv = (const float*)d_in[3];
    const float* Wo = (const float*)d_in[4];
    const float* bo = (const float*)d_in[5];
    float* out = (float*)d_out;

    float* Q   = (float*)d_ws;                 // 16 MB each; Ctx aliases Q (safe, see attn_kernel)
    float* Kp  = Q  + (size_t)M * D;
    float* Vp  = Kp + (size_t)M * D;
    float* Ctx = Q;

    dim3 blk(32, 8);
    dim3 grd(D / 32, M / 32);
    gemm_qkv<<<grd, blk, 0, stream>>>(x, Wq, Q);
    gemm_qkv<<<grd, blk, 0, stream>>>(x, Wk, Kp);
    gemm_qkv<<<grd, blk, 0, stream>>>(x, Wv, Vp);
    attn_kernel<<<dim3(S, B * NH), 256, 0, stream>>>(Q, Kp, Vp, Ctx);
    gemm_out<<<grd, blk, 0, stream>>>(Ctx, Wo, bo, out);
}

// Round 4
// 1561.674 us; speedup vs baseline: 3.2426x; 3.2426x over previous
//
#include <hip/hip_runtime.h>
#include <hip/hip_bf16.h>

#define B 2
#define S 2048
#define D 1024
#define NH 16
#define DH 64
#define M (B*S)
#define BQ 128
#define BK 64

typedef __hip_bfloat16 bf16;
typedef __attribute__((ext_vector_type(8))) short frag_ab;   // 8 bf16
typedef __attribute__((ext_vector_type(4))) float frag_cd;   // 4 f32
typedef __attribute__((ext_vector_type(4))) unsigned int u32x4; // 16B chunk

// ---------- GEMM: Out[m,n] = sum_k X[m,k]*W[k,n]; fp32 in, bf16 out (for attention)
__global__ __launch_bounds__(256) void gemm_qkv(const float* __restrict__ X,
                                                const float* __restrict__ W,
                                                bf16* __restrict__ Out) {
    __shared__ float Xs[32][33];
    __shared__ float Ws[32][33];
    const int tx = threadIdx.x;          // 0..31
    const int ty = threadIdx.y;          // 0..7
    const int row0 = blockIdx.y * 32;
    const int col0 = blockIdx.x * 32;
    float acc[4] = {0.f, 0.f, 0.f, 0.f};
    for (int k0 = 0; k0 < D; k0 += 32) {
#pragma unroll
        for (int i = 0; i < 4; i++) {
            int r = ty + 8 * i;
            Xs[r][tx] = X[(size_t)(row0 + r) * D + k0 + tx];
            Ws[r][tx] = W[(size_t)(k0 + r) * D + col0 + tx];
        }
        __syncthreads();
#pragma unroll
        for (int kk = 0; kk < 32; kk++) {
            float w = Ws[kk][tx];
#pragma unroll
            for (int i = 0; i < 4; i++) acc[i] += Xs[ty * 4 + i][kk] * w;
        }
        __syncthreads();
    }
#pragma unroll
    for (int i = 0; i < 4; i++)
        Out[(size_t)(row0 + ty * 4 + i) * D + col0 + tx] = __float2bfloat16(acc[i]);
}

// ---------- Output projection: Out = Ctx @ Wo + bo, fp32 everywhere
__global__ __launch_bounds__(256) void gemm_out(const float* __restrict__ X,
                                                const float* __restrict__ W,
                                                const float* __restrict__ bias,
                                                float* __restrict__ Out) {
    __shared__ float Xs[32][33];
    __shared__ float Ws[32][33];
    const int tx = threadIdx.x;
    const int ty = threadIdx.y;
    const int row0 = blockIdx.y * 32;
    const int col0 = blockIdx.x * 32;
    float acc[4] = {0.f, 0.f, 0.f, 0.f};
    for (int k0 = 0; k0 < D; k0 += 32) {
#pragma unroll
        for (int i = 0; i < 4; i++) {
            int r = ty + 8 * i;
            Xs[r][tx] = X[(size_t)(row0 + r) * D + k0 + tx];
            Ws[r][tx] = W[(size_t)(k0 + r) * D + col0 + tx];
        }
        __syncthreads();
#pragma unroll
        for (int kk = 0; kk < 32; kk++) {
            float w = Ws[kk][tx];
#pragma unroll
            for (int i = 0; i < 4; i++) acc[i] += Xs[ty * 4 + i][kk] * w;
        }
        __syncthreads();
    }
    const float bv = bias[col0 + tx];
#pragma unroll
    for (int i = 0; i < 4; i++)
        Out[(size_t)(row0 + ty * 4 + i) * D + col0 + tx] = acc[i] + bv;
}

// ---------- Flash attention with MFMA. Q,K,V bf16 [B,S,D]; Ctx fp32 [B,S,D].
// One block per (b*h, q-tile of 128). 4 waves; wave owns 32 q-rows.
__global__ __launch_bounds__(256) void attn_mfma(const bf16* __restrict__ Q,
                                                 const bf16* __restrict__ K,
                                                 const bf16* __restrict__ V,
                                                 float* __restrict__ Ctx) {
    // +8 bf16 pad -> row stride 36 dwords: b128 frag reads hit the 8-dw/bank floor
    __shared__ __align__(16) bf16 Qs[BQ][DH + 8];
    __shared__ __align__(16) bf16 Ks[BK][DH + 8];
    __shared__ __align__(16) bf16 Vt[DH][BK + 8];   // V transposed: [dim][key]
    __shared__ __align__(16) bf16 Ps[BQ][BK + 8];   // P: [q-row][key], wave-private rows

    const int tid  = threadIdx.x;
    const int wave = tid >> 6;
    const int lane = tid & 63;
    const int r16  = lane & 15;
    const int quad = lane >> 4;

    const int bh = blockIdx.x;
    const int jy = blockIdx.y;
    const int qt = (jy < 8) ? jy : 23 - jy;   // pair-balanced q-tile order
    const int b  = bh >> 4, h = bh & 15;
    const size_t base = (size_t)b * S * D + (size_t)h * DH;
    const int q0 = qt * BQ;

    // ---- stage Q tile (128 x 64) coalesced, 16B chunks
#pragma unroll
    for (int i = tid; i < BQ * (DH / 8); i += 256) {
        int r = i >> 3, c8 = (i & 7) * 8;
        *(u32x4*)&Qs[r][c8] = *(const u32x4*)(Q + base + (size_t)(q0 + r) * D + c8);
    }

    // softmax state per lane: rows quad*4+reg of each 16-row m-tile
    float mrow[2][4], lrow[2][4];
    frag_cd Oacc[2][4];
#pragma unroll
    for (int mt = 0; mt < 2; mt++)
#pragma unroll
        for (int rg = 0; rg < 4; rg++) {
            mrow[mt][rg] = -1e30f;
            lrow[mt][rg] = 0.f;
            Oacc[mt][rg] = frag_cd{0.f, 0.f, 0.f, 0.f};
        }

    const int nkt = 2 * qt + 2;
    for (int kt = 0; kt < nkt; kt++) {
        const int k0 = kt * BK;
        __syncthreads();   // prev iter done reading Ks/Vt/Ps

        // stage K tile (64 x 64)
#pragma unroll
        for (int i = tid; i < BK * (DH / 8); i += 256) {
            int r = i >> 3, c8 = (i & 7) * 8;
            *(u32x4*)&Ks[r][c8] = *(const u32x4*)(K + base + (size_t)(k0 + r) * D + c8);
        }
        // stage V transposed: thread -> (key = lane, dim block = wave*16)
        {
            const int key = tid & 63, dg = tid >> 6;
            const bf16* vp = V + base + (size_t)(k0 + key) * D + dg * 16;
            bf16 e[16];
            *(u32x4*)&e[0] = *(const u32x4*)vp;
            *(u32x4*)&e[8] = *(const u32x4*)(vp + 8);
#pragma unroll
            for (int jj = 0; jj < 16; jj++) Vt[dg * 16 + jj][key] = e[jj];
        }
        __syncthreads();

        // ---- QK^T: S[128q x 64k] per block; wave does 2 m-tiles x 4 n-tiles
        frag_ab aq[2][2], bk[4][2];
#pragma unroll
        for (int mt = 0; mt < 2; mt++)
#pragma unroll
            for (int ks = 0; ks < 2; ks++)
                aq[mt][ks] = *(const frag_ab*)&Qs[wave * 32 + mt * 16 + r16][ks * 32 + quad * 8];
#pragma unroll
        for (int nt = 0; nt < 4; nt++)
#pragma unroll
            for (int ks = 0; ks < 2; ks++)
                bk[nt][ks] = *(const frag_ab*)&Ks[nt * 16 + r16][ks * 32 + quad * 8];

        frag_cd Sacc[2][4];
#pragma unroll
        for (int mt = 0; mt < 2; mt++)
#pragma unroll
            for (int nt = 0; nt < 4; nt++) {
                Sacc[mt][nt] = frag_cd{0.f, 0.f, 0.f, 0.f};
#pragma unroll
                for (int ks = 0; ks < 2; ks++)
                    Sacc[mt][nt] = __builtin_amdgcn_mfma_f32_16x16x32_bf16(
                        aq[mt][ks], bk[nt][ks], Sacc[mt][nt], 0, 0, 0);
            }

        // ---- online softmax (C-layout: col=lane&15, row=quad*4+reg)
        const bool domask = (kt >= 2 * qt);
#pragma unroll
        for (int mt = 0; mt < 2; mt++) {
#pragma unroll
            for (int rg = 0; rg < 4; rg++) {
                const int row = q0 + wave * 32 + mt * 16 + quad * 4 + rg;
                float mx = -1e30f;
#pragma unroll
                for (int nt = 0; nt < 4; nt++) {
                    float s = Sacc[mt][nt][rg] * 0.125f;   // 1/sqrt(64)
                    if (domask) {
                        int col = k0 + nt * 16 + r16;
                        s = (col <= row) ? s : -1e30f;
                    }
                    Sacc[mt][nt][rg] = s;
                    mx = fmaxf(mx, s);
                }
                mx = fmaxf(mx, __shfl_xor(mx, 1, 64));
                mx = fmaxf(mx, __shfl_xor(mx, 2, 64));
                mx = fmaxf(mx, __shfl_xor(mx, 4, 64));
                mx = fmaxf(mx, __shfl_xor(mx, 8, 64));
                const float mnew  = fmaxf(mrow[mt][rg], mx);
                const float alpha = __expf(mrow[mt][rg] - mnew);
                mrow[mt][rg] = mnew;
                float rsum = 0.f;
#pragma unroll
                for (int nt = 0; nt < 4; nt++) {
                    float p = __expf(Sacc[mt][nt][rg] - mnew);
                    Sacc[mt][nt][rg] = p;
                    rsum += p;
                }
                rsum += __shfl_xor(rsum, 1, 64);
                rsum += __shfl_xor(rsum, 2, 64);
                rsum += __shfl_xor(rsum, 4, 64);
                rsum += __shfl_xor(rsum, 8, 64);
                lrow[mt][rg] = lrow[mt][rg] * alpha + rsum;
#pragma unroll
                for (int nd = 0; nd < 4; nd++) Oacc[mt][nd][rg] *= alpha;
            }
            // write P (bf16) to wave-private LDS rows
#pragma unroll
            for (int nt = 0; nt < 4; nt++)
#pragma unroll
                for (int rg = 0; rg < 4; rg++)
                    Ps[wave * 32 + mt * 16 + quad * 4 + rg][nt * 16 + r16] =
                        __float2bfloat16(Sacc[mt][nt][rg]);
        }
        // no barrier: Ps rows are wave-private; LDS ops complete in-order per wave

        // ---- PV: O[128q x 64d] += P[128q x 64k] * V[64k x 64d]
        frag_ab ap[2][2], bv[4][2];
#pragma unroll
        for (int mt = 0; mt < 2; mt++)
#pragma unroll
            for (int ks = 0; ks < 2; ks++)
                ap[mt][ks] = *(const frag_ab*)&Ps[wave * 32 + mt * 16 + r16][ks * 32 + quad * 8];
#pragma unroll
        for (int nd = 0; nd < 4; nd++)
#pragma unroll
            for (int ks = 0; ks < 2; ks++)
                bv[nd][ks] = *(const frag_ab*)&Vt[nd * 16 + r16][ks * 32 + quad * 8];
#pragma unroll
        for (int mt = 0; mt < 2; mt++)
#pragma unroll
            for (int nd = 0; nd < 4; nd++)
#pragma unroll
                for (int ks = 0; ks < 2; ks++)
                    Oacc[mt][nd] = __builtin_amdgcn_mfma_f32_16x16x32_bf16(
                        ap[mt][ks], bv[nd][ks], Oacc[mt][nd], 0, 0, 0);
    }

    // ---- epilogue: Ctx = O / l
#pragma unroll
    for (int mt = 0; mt < 2; mt++)
#pragma unroll
        for (int rg = 0; rg < 4; rg++) {
            const float invl = 1.f / lrow[mt][rg];
            const int row = q0 + wave * 32 + mt * 16 + quad * 4 + rg;
#pragma unroll
            for (int nd = 0; nd < 4; nd++) {
                const int dim = nd * 16 + r16;
                Ctx[base + (size_t)row * D + dim] = Oacc[mt][nd][rg] * invl;
            }
        }
}

extern "C" void kernel_launch(void* const* d_in, const int* in_sizes, int n_in,
                              void* d_out, int out_size, void* d_ws, size_t ws_size,
                              hipStream_t stream) {
    const float* x  = (const float*)d_in[0];
    const float* Wq = (const float*)d_in[1];
    const float* Wk = (const float*)d_in[2];
    const float* Wv = (const float*)d_in[3];
    const float* Wo = (const float*)d_in[4];
    const float* bo = (const float*)d_in[5];
    float* out = (float*)d_out;

    bf16* Qb  = (bf16*)d_ws;                         // 8 MB
    bf16* Kb  = Qb + (size_t)M * D;                  // 8 MB
    bf16* Vb  = Kb + (size_t)M * D;                  // 8 MB
    float* Ctx = (float*)(Vb + (size_t)M * D);       // 16 MB

    dim3 blk(32, 8);
    dim3 grd(D / 32, M / 32);
    gemm_qkv<<<grd, blk, 0, stream>>>(x, Wq, Qb);
    gemm_qkv<<<grd, blk, 0, stream>>>(x, Wk, Kb);
    gemm_qkv<<<grd, blk, 0, stream>>>(x, Wv, Vb);
    attn_mfma<<<dim3(B * NH, S / BQ), 256, 0, stream>>>(Qb, Kb, Vb, Ctx);
    gemm_out<<<grd, blk, 0, stream>>>(Ctx, Wo, bo, out);
}

// Round 5
// 296.205 us; speedup vs baseline: 17.0957x; 5.2723x over previous
//
#include <hip/hip_runtime.h>
#include <hip/hip_bf16.h>

#define B 2
#define S 2048
#define D 1024
#define NH 16
#define DH 64
#define M (B*S)
#define BQ 128
#define BK 64

typedef __hip_bfloat16 bf16;
typedef __attribute__((ext_vector_type(8))) short frag_ab;   // 8 bf16
typedef __attribute__((ext_vector_type(4))) float frag_cd;   // 4 f32
typedef __attribute__((ext_vector_type(4))) unsigned int u32x4; // 16B chunk

// async global->LDS, 16B per lane; LDS dest = wave-uniform base + lane*16
__device__ __forceinline__ void gload_lds16(const bf16* g, bf16* l) {
    __builtin_amdgcn_global_load_lds((const __attribute__((address_space(1))) unsigned int*)g,
                                     (__attribute__((address_space(3))) unsigned int*)l,
                                     16, 0, 0);
}

// ---------- convert x fp32 -> bf16 (row-major)
__global__ __launch_bounds__(256) void cvt_x(const float* __restrict__ x, bf16* __restrict__ xb) {
    const int i = (blockIdx.x * 256 + threadIdx.x) * 4;
    const float4 v = *(const float4*)(x + i);
    __align__(8) bf16 t[4] = {__float2bfloat16(v.x), __float2bfloat16(v.y),
                              __float2bfloat16(v.z), __float2bfloat16(v.w)};
    *(unsigned long long*)(xb + i) = *(const unsigned long long*)t;
}

// ---------- convert + transpose all 4 weights: T[n][k] = W[k][n], fp32 -> bf16
__global__ __launch_bounds__(256) void cvt_wT(const float* __restrict__ W0, const float* __restrict__ W1,
                                              const float* __restrict__ W2, const float* __restrict__ W3,
                                              bf16* __restrict__ T0, bf16* __restrict__ T1,
                                              bf16* __restrict__ T2, bf16* __restrict__ T3) {
    const float* src; bf16* dst;
    switch (blockIdx.z) {
        case 0: src = W0; dst = T0; break;
        case 1: src = W1; dst = T1; break;
        case 2: src = W2; dst = T2; break;
        default: src = W3; dst = T3; break;
    }
    __shared__ float t[32][33];
    const int tx = threadIdx.x & 31, ty = threadIdx.x >> 5;
    const int c0 = blockIdx.x * 32, r0 = blockIdx.y * 32;
#pragma unroll
    for (int i = 0; i < 4; i++)
        t[ty + 8 * i][tx] = src[(size_t)(r0 + ty + 8 * i) * D + c0 + tx];
    __syncthreads();
#pragma unroll
    for (int i = 0; i < 4; i++)
        dst[(size_t)(c0 + ty + 8 * i) * D + r0 + tx] = __float2bfloat16(t[tx][ty + 8 * i]);
}

// ---------- bf16 MFMA GEMM: C[m,n] = A[m,k] * Bt[n,k]; 128x128 tile, BK=64.
// XOR-swizzled LDS: (row, colblock) stored at row*64 + ((cb ^ (row&7))*8) elems.
// Staging slot s (=lane order) covers row=s>>3, cb=s&7 -> global colblock (s&7)^(row&7),
// so LDS writes are lane-contiguous (global_load_lds requirement) and frag
// ds_read_b128 hits the uniform 8-dword/bank floor.
template <bool ADD_BIAS, typename CT>
__device__ __forceinline__ void gemm_body(const bf16* __restrict__ A, const bf16* __restrict__ Bt,
                                          const float* __restrict__ bias, CT* __restrict__ C) {
    __shared__ __align__(16) bf16 As[128 * BK];
    __shared__ __align__(16) bf16 Bs[128 * BK];
    const int tid  = threadIdx.x;
    const int wave = tid >> 6;
    const int lane = tid & 63;
    const int r16  = lane & 15;
    const int quad = lane >> 4;
    const int row0 = blockIdx.y * 128;
    const int col0 = blockIdx.x * 128;
    const int wm = (wave & 1) * 64;
    const int wn = (wave >> 1) * 64;

    frag_cd acc[4][4];
#pragma unroll
    for (int mt = 0; mt < 4; mt++)
#pragma unroll
        for (int nt = 0; nt < 4; nt++) acc[mt][nt] = frag_cd{0.f, 0.f, 0.f, 0.f};

    for (int k0 = 0; k0 < D; k0 += BK) {
        __syncthreads();   // previous tile fully consumed
#pragma unroll
        for (int j = 0; j < 4; j++) {
            const int s = wave * 256 + j * 64 + lane;
            const int r = s >> 3;
            const int c = (s & 7) ^ (r & 7);
            bf16* ldsA = &As[(wave * 256 + j * 64) * 8];   // wave-uniform base
            bf16* ldsB = &Bs[(wave * 256 + j * 64) * 8];
            gload_lds16(A  + (size_t)(row0 + r) * D + k0 + c * 8, ldsA);
            gload_lds16(Bt + (size_t)(col0 + r) * D + k0 + c * 8, ldsB);
        }
        __syncthreads();   // drains vmcnt (compiler inserts waitcnt before barrier)

        frag_ab af[4][2], bf[4][2];
#pragma unroll
        for (int mt = 0; mt < 4; mt++) {
            const int row = wm + mt * 16 + r16;
#pragma unroll
            for (int ks = 0; ks < 2; ks++) {
                const int c8 = ks * 4 + quad;
                af[mt][ks] = *(const frag_ab*)&As[row * 64 + ((c8 ^ (row & 7)) * 8)];
            }
        }
#pragma unroll
        for (int nt = 0; nt < 4; nt++) {
            const int row = wn + nt * 16 + r16;
#pragma unroll
            for (int ks = 0; ks < 2; ks++) {
                const int c8 = ks * 4 + quad;
                bf[nt][ks] = *(const frag_ab*)&Bs[row * 64 + ((c8 ^ (row & 7)) * 8)];
            }
        }
#pragma unroll
        for (int mt = 0; mt < 4; mt++)
#pragma unroll
            for (int nt = 0; nt < 4; nt++)
#pragma unroll
                for (int ks = 0; ks < 2; ks++)
                    acc[mt][nt] = __builtin_amdgcn_mfma_f32_16x16x32_bf16(
                        af[mt][ks], bf[nt][ks], acc[mt][nt], 0, 0, 0);
    }

    // epilogue: C layout col=r16, row=quad*4+rg
#pragma unroll
    for (int mt = 0; mt < 4; mt++)
#pragma unroll
        for (int nt = 0; nt < 4; nt++) {
            const int col = col0 + wn + nt * 16 + r16;
            const float bv = ADD_BIAS ? bias[col] : 0.f;
#pragma unroll
            for (int rg = 0; rg < 4; rg++) {
                const int row = row0 + wm + mt * 16 + quad * 4 + rg;
                const float v = acc[mt][nt][rg] + bv;
                if constexpr (sizeof(CT) == 2)
                    C[(size_t)row * D + col] = (CT)__float2bfloat16(v);
                else
                    C[(size_t)row * D + col] = (CT)v;
            }
        }
}

__global__ __launch_bounds__(256) void gemm_bf16(const bf16* __restrict__ A, const bf16* __restrict__ Bt,
                                                 bf16* __restrict__ C) {
    gemm_body<false, bf16>(A, Bt, nullptr, C);
}

__global__ __launch_bounds__(256) void gemm_bf16_bias(const bf16* __restrict__ A, const bf16* __restrict__ Bt,
                                                      const float* __restrict__ bias, float* __restrict__ C) {
    gemm_body<true, float>(A, Bt, bias, C);
}

// ---------- Flash attention with MFMA. Q,K,V bf16 [B,S,D]; Ctx bf16 [B,S,D].
__global__ __launch_bounds__(256) void attn_mfma(const bf16* __restrict__ Q,
                                                 const bf16* __restrict__ K,
                                                 const bf16* __restrict__ V,
                                                 bf16* __restrict__ Ctx) {
    __shared__ __align__(16) bf16 Qs[BQ][DH + 8];
    __shared__ __align__(16) bf16 Ks[BK][DH + 8];
    __shared__ __align__(16) bf16 Vt[DH][BK + 8];   // V transposed: [dim][key]
    __shared__ __align__(16) bf16 Ps[BQ][BK + 8];   // P: [q-row][key], wave-private rows

    const int tid  = threadIdx.x;
    const int wave = tid >> 6;
    const int lane = tid & 63;
    const int r16  = lane & 15;
    const int quad = lane >> 4;

    const int bh = blockIdx.x;
    const int jy = blockIdx.y;
    const int qt = (jy < 8) ? jy : 23 - jy;   // pair-balanced q-tile order
    const int b  = bh >> 4, h = bh & 15;
    const size_t base = (size_t)b * S * D + (size_t)h * DH;
    const int q0 = qt * BQ;

#pragma unroll
    for (int i = tid; i < BQ * (DH / 8); i += 256) {
        int r = i >> 3, c8 = (i & 7) * 8;
        *(u32x4*)&Qs[r][c8] = *(const u32x4*)(Q + base + (size_t)(q0 + r) * D + c8);
    }

    float mrow[2][4], lrow[2][4];
    frag_cd Oacc[2][4];
#pragma unroll
    for (int mt = 0; mt < 2; mt++)
#pragma unroll
        for (int rg = 0; rg < 4; rg++) {
            mrow[mt][rg] = -1e30f;
            lrow[mt][rg] = 0.f;
            Oacc[mt][rg] = frag_cd{0.f, 0.f, 0.f, 0.f};
        }

    const int nkt = 2 * qt + 2;
    for (int kt = 0; kt < nkt; kt++) {
        const int k0 = kt * BK;
        __syncthreads();

#pragma unroll
        for (int i = tid; i < BK * (DH / 8); i += 256) {
            int r = i >> 3, c8 = (i & 7) * 8;
            *(u32x4*)&Ks[r][c8] = *(const u32x4*)(K + base + (size_t)(k0 + r) * D + c8);
        }
        {
            const int key = tid & 63, dg = tid >> 6;
            const bf16* vp = V + base + (size_t)(k0 + key) * D + dg * 16;
            bf16 e[16];
            *(u32x4*)&e[0] = *(const u32x4*)vp;
            *(u32x4*)&e[8] = *(const u32x4*)(vp + 8);
#pragma unroll
            for (int jj = 0; jj < 16; jj++) Vt[dg * 16 + jj][key] = e[jj];
        }
        __syncthreads();

        frag_ab aq[2][2], bk[4][2];
#pragma unroll
        for (int mt = 0; mt < 2; mt++)
#pragma unroll
            for (int ks = 0; ks < 2; ks++)
                aq[mt][ks] = *(const frag_ab*)&Qs[wave * 32 + mt * 16 + r16][ks * 32 + quad * 8];
#pragma unroll
        for (int nt = 0; nt < 4; nt++)
#pragma unroll
            for (int ks = 0; ks < 2; ks++)
                bk[nt][ks] = *(const frag_ab*)&Ks[nt * 16 + r16][ks * 32 + quad * 8];

        frag_cd Sacc[2][4];
#pragma unroll
        for (int mt = 0; mt < 2; mt++)
#pragma unroll
            for (int nt = 0; nt < 4; nt++) {
                Sacc[mt][nt] = frag_cd{0.f, 0.f, 0.f, 0.f};
#pragma unroll
                for (int ks = 0; ks < 2; ks++)
                    Sacc[mt][nt] = __builtin_amdgcn_mfma_f32_16x16x32_bf16(
                        aq[mt][ks], bk[nt][ks], Sacc[mt][nt], 0, 0, 0);
            }

        const bool domask = (kt >= 2 * qt);
#pragma unroll
        for (int mt = 0; mt < 2; mt++) {
#pragma unroll
            for (int rg = 0; rg < 4; rg++) {
                const int row = q0 + wave * 32 + mt * 16 + quad * 4 + rg;
                float mx = -1e30f;
#pragma unroll
                for (int nt = 0; nt < 4; nt++) {
                    float s = Sacc[mt][nt][rg] * 0.125f;
                    if (domask) {
                        int col = k0 + nt * 16 + r16;
                        s = (col <= row) ? s : -1e30f;
                    }
                    Sacc[mt][nt][rg] = s;
                    mx = fmaxf(mx, s);
                }
                mx = fmaxf(mx, __shfl_xor(mx, 1, 64));
                mx = fmaxf(mx, __shfl_xor(mx, 2, 64));
                mx = fmaxf(mx, __shfl_xor(mx, 4, 64));
                mx = fmaxf(mx, __shfl_xor(mx, 8, 64));
                const float mnew  = fmaxf(mrow[mt][rg], mx);
                const float alpha = __expf(mrow[mt][rg] - mnew);
                mrow[mt][rg] = mnew;
                float rsum = 0.f;
#pragma unroll
                for (int nt = 0; nt < 4; nt++) {
                    float p = __expf(Sacc[mt][nt][rg] - mnew);
                    Sacc[mt][nt][rg] = p;
                    rsum += p;
                }
                rsum += __shfl_xor(rsum, 1, 64);
                rsum += __shfl_xor(rsum, 2, 64);
                rsum += __shfl_xor(rsum, 4, 64);
                rsum += __shfl_xor(rsum, 8, 64);
                lrow[mt][rg] = lrow[mt][rg] * alpha + rsum;
#pragma unroll
                for (int nd = 0; nd < 4; nd++) Oacc[mt][nd][rg] *= alpha;
            }
#pragma unroll
            for (int nt = 0; nt < 4; nt++)
#pragma unroll
                for (int rg = 0; rg < 4; rg++)
                    Ps[wave * 32 + mt * 16 + quad * 4 + rg][nt * 16 + r16] =
                        __float2bfloat16(Sacc[mt][nt][rg]);
        }
        // no barrier: Ps rows are wave-private; per-wave LDS ops are in-order

        frag_ab ap[2][2], bv[4][2];
#pragma unroll
        for (int mt = 0; mt < 2; mt++)
#pragma unroll
            for (int ks = 0; ks < 2; ks++)
                ap[mt][ks] = *(const frag_ab*)&Ps[wave * 32 + mt * 16 + r16][ks * 32 + quad * 8];
#pragma unroll
        for (int nd = 0; nd < 4; nd++)
#pragma unroll
            for (int ks = 0; ks < 2; ks++)
                bv[nd][ks] = *(const frag_ab*)&Vt[nd * 16 + r16][ks * 32 + quad * 8];
#pragma unroll
        for (int mt = 0; mt < 2; mt++)
#pragma unroll
            for (int nd = 0; nd < 4; nd++)
#pragma unroll
                for (int ks = 0; ks < 2; ks++)
                    Oacc[mt][nd] = __builtin_amdgcn_mfma_f32_16x16x32_bf16(
                        ap[mt][ks], bv[nd][ks], Oacc[mt][nd], 0, 0, 0);
    }

#pragma unroll
    for (int mt = 0; mt < 2; mt++)
#pragma unroll
        for (int rg = 0; rg < 4; rg++) {
            const float invl = 1.f / lrow[mt][rg];
            const int row = q0 + wave * 32 + mt * 16 + quad * 4 + rg;
#pragma unroll
            for (int nd = 0; nd < 4; nd++) {
                const int dim = nd * 16 + r16;
                Ctx[base + (size_t)row * D + dim] =
                    __float2bfloat16(Oacc[mt][nd][rg] * invl);
            }
        }
}

extern "C" void kernel_launch(void* const* d_in, const int* in_sizes, int n_in,
                              void* d_out, int out_size, void* d_ws, size_t ws_size,
                              hipStream_t stream) {
    const float* x  = (const float*)d_in[0];
    const float* Wq = (const float*)d_in[1];
    const float* Wk = (const float*)d_in[2];
    const float* Wv = (const float*)d_in[3];
    const float* Wo = (const float*)d_in[4];
    const float* bo = (const float*)d_in[5];
    float* out = (float*)d_out;

    bf16* xb   = (bf16*)d_ws;                    // 4M elems
    bf16* WqT  = xb   + (size_t)M * D;           // 1M each
    bf16* WkT  = WqT  + (size_t)D * D;
    bf16* WvT  = WkT  + (size_t)D * D;
    bf16* WoT  = WvT  + (size_t)D * D;
    bf16* Qb   = WoT  + (size_t)D * D;           // 4M each
    bf16* Kb   = Qb   + (size_t)M * D;
    bf16* Vb   = Kb   + (size_t)M * D;
    bf16* Ctxb = Vb   + (size_t)M * D;

    cvt_x<<<(M * D) / 1024, 256, 0, stream>>>(x, xb);
    cvt_wT<<<dim3(32, 32, 4), 256, 0, stream>>>(Wq, Wk, Wv, Wo, WqT, WkT, WvT, WoT);

    dim3 grd(D / 128, M / 128);   // 8 x 32
    gemm_bf16<<<grd, 256, 0, stream>>>(xb, WqT, Qb);
    gemm_bf16<<<grd, 256, 0, stream>>>(xb, WkT, Kb);
    gemm_bf16<<<grd, 256, 0, stream>>>(xb, WvT, Vb);
    attn_mfma<<<dim3(B * NH, S / BQ), 256, 0, stream>>>(Qb, Kb, Vb, Ctxb);
    gemm_bf16_bias<<<grd, 256, 0, stream>>>(Ctxb, WoT, bo, out);
}

// Round 6
// 220.994 us; speedup vs baseline: 22.9139x; 1.3403x over previous
//
#include <hip/hip_runtime.h>
#include <hip/hip_bf16.h>

#define B 2
#define S 2048
#define D 1024
#define NH 16
#define DH 64
#define M (B*S)
#define BQ 128
#define BK 64
#define KSCALE 0.18033688011112042f   // (1/sqrt(64)) * log2(e)

typedef __hip_bfloat16 bf16;
typedef __attribute__((ext_vector_type(8))) short frag_ab;   // 8 bf16
typedef __attribute__((ext_vector_type(4))) float frag_cd;   // 4 f32
typedef unsigned long long ull;

// async global->LDS, 16B/lane; LDS dest = wave-uniform base + lane*16
__device__ __forceinline__ void gload_lds16(const bf16* g, bf16* l) {
    __builtin_amdgcn_global_load_lds((const __attribute__((address_space(1))) unsigned int*)g,
                                     (__attribute__((address_space(3))) unsigned int*)l,
                                     16, 0, 0);
}

// ---------- convert x fp32 -> bf16
__global__ __launch_bounds__(256) void cvt_x(const float* __restrict__ x, bf16* __restrict__ xb) {
    const int i = (blockIdx.x * 256 + threadIdx.x) * 4;
    const float4 v = *(const float4*)(x + i);
    __align__(8) bf16 t[4] = {__float2bfloat16(v.x), __float2bfloat16(v.y),
                              __float2bfloat16(v.z), __float2bfloat16(v.w)};
    *(ull*)(xb + i) = *(const ull*)t;
}

// ---------- convert + transpose weights: T[n][k] = W[k][n]
__global__ __launch_bounds__(256) void cvt_wT(const float* __restrict__ W0, const float* __restrict__ W1,
                                              const float* __restrict__ W2, const float* __restrict__ W3,
                                              bf16* __restrict__ T0, bf16* __restrict__ T1,
                                              bf16* __restrict__ T2, bf16* __restrict__ T3) {
    const float* src; bf16* dst;
    switch (blockIdx.z) {
        case 0: src = W0; dst = T0; break;
        case 1: src = W1; dst = T1; break;
        case 2: src = W2; dst = T2; break;
        default: src = W3; dst = T3; break;
    }
    __shared__ float t[32][33];
    const int tx = threadIdx.x & 31, ty = threadIdx.x >> 5;
    const int c0 = blockIdx.x * 32, r0 = blockIdx.y * 32;
#pragma unroll
    for (int i = 0; i < 4; i++)
        t[ty + 8 * i][tx] = src[(size_t)(r0 + ty + 8 * i) * D + c0 + tx];
    __syncthreads();
#pragma unroll
    for (int i = 0; i < 4; i++)
        dst[(size_t)(c0 + ty + 8 * i) * D + r0 + tx] = __float2bfloat16(t[tx][ty + 8 * i]);
}

// ---------- fused QKV GEMM: C = xb @ [WqT|WkT|WvT]^T, 128x128 tiles, grid (24,32).
// Q/K thirds stored row-major; V third stored TRANSPOSED per head: Vt[bh][d][s].
__global__ __launch_bounds__(256) void gemm_qkv_all(const bf16* __restrict__ A, const bf16* __restrict__ Bt,
                                                    bf16* __restrict__ Qb, bf16* __restrict__ Kb,
                                                    bf16* __restrict__ Vt_g) {
    __shared__ __align__(16) bf16 As[128 * BK];
    __shared__ __align__(16) bf16 Bs[128 * BK];
    const int tid = threadIdx.x, wave = tid >> 6, lane = tid & 63;
    const int r16 = lane & 15, quad = lane >> 4;
    const int row0 = blockIdx.y * 128;
    const int col0 = blockIdx.x * 128;
    const int wm = (wave & 1) * 64, wn = (wave >> 1) * 64;

    frag_cd acc[4][4];
#pragma unroll
    for (int mt = 0; mt < 4; mt++)
#pragma unroll
        for (int nt = 0; nt < 4; nt++) acc[mt][nt] = frag_cd{0.f, 0.f, 0.f, 0.f};

    for (int k0 = 0; k0 < D; k0 += BK) {
        __syncthreads();
#pragma unroll
        for (int j = 0; j < 4; j++) {
            const int s = wave * 256 + j * 64 + lane;
            const int r = s >> 3;
            const int c = (s ^ r) & 7;
            gload_lds16(A  + (size_t)(row0 + r) * D + k0 + c * 8, &As[(wave * 256 + j * 64) * 8]);
            gload_lds16(Bt + (size_t)(col0 + r) * D + k0 + c * 8, &Bs[(wave * 256 + j * 64) * 8]);
        }
        __syncthreads();

        frag_ab af[4][2], bf[4][2];
#pragma unroll
        for (int mt = 0; mt < 4; mt++) {
            const int row = wm + mt * 16 + r16;
#pragma unroll
            for (int ks = 0; ks < 2; ks++)
                af[mt][ks] = *(const frag_ab*)&As[row * 64 + (((ks * 4 + quad) ^ (row & 7)) * 8)];
        }
#pragma unroll
        for (int nt = 0; nt < 4; nt++) {
            const int row = wn + nt * 16 + r16;
#pragma unroll
            for (int ks = 0; ks < 2; ks++)
                bf[nt][ks] = *(const frag_ab*)&Bs[row * 64 + (((ks * 4 + quad) ^ (row & 7)) * 8)];
        }
#pragma unroll
        for (int mt = 0; mt < 4; mt++)
#pragma unroll
            for (int nt = 0; nt < 4; nt++)
#pragma unroll
                for (int ks = 0; ks < 2; ks++)
                    acc[mt][nt] = __builtin_amdgcn_mfma_f32_16x16x32_bf16(
                        af[mt][ks], bf[nt][ks], acc[mt][nt], 0, 0, 0);
    }

    const int third = col0 >> 10;
    if (third < 2) {
        bf16* Out = (third == 0) ? Qb : Kb;
#pragma unroll
        for (int mt = 0; mt < 4; mt++)
#pragma unroll
            for (int nt = 0; nt < 4; nt++) {
                const int cl = (col0 + wn + nt * 16 + r16) & 1023;
#pragma unroll
                for (int rg = 0; rg < 4; rg++) {
                    const int row = row0 + wm + mt * 16 + quad * 4 + rg;
                    Out[(size_t)row * D + cl] = __float2bfloat16(acc[mt][nt][rg]);
                }
            }
    } else {
        const int bb = row0 >> 11;
        const int sb0 = (row0 & 2047) + wm;
#pragma unroll
        for (int mt = 0; mt < 4; mt++)
#pragma unroll
            for (int nt = 0; nt < 4; nt++) {
                const int c  = (col0 + wn + nt * 16 + r16) - 2048;
                const int hh = c >> 6, dl = c & 63;
                const int sb = sb0 + mt * 16 + quad * 4;
                __align__(8) bf16 t4[4];
#pragma unroll
                for (int rg = 0; rg < 4; rg++) t4[rg] = __float2bfloat16(acc[mt][nt][rg]);
                *(ull*)(Vt_g + (((size_t)bb * 16 + hh) * 64 + dl) * S + sb) = *(const ull*)t4;
            }
    }
}

// ---------- Flash attention, S^T formulation. Q,K bf16 [B,S,D]; Vg = Vt[bh][d][s]; Ctx bf16 [B,S,D].
__global__ __launch_bounds__(256, 4) void attn_mfma(const bf16* __restrict__ Q,
                                                    const bf16* __restrict__ K,
                                                    const bf16* __restrict__ Vg,
                                                    bf16* __restrict__ Ctx) {
    __shared__ __align__(16) char smem[34816];
    bf16* Ks = (bf16*)smem;            // [64][64] swizzled (rows=key)
    bf16* Vt = (bf16*)(smem + 8192);   // [64][64] swizzled (rows=dim, cols=key)
    bf16* Qs = (bf16*)(smem + 16384);  // [128][64] swizzled (staging only)
    bf16* Ps = (bf16*)(smem + 16384);  // [128][72] padded; overlays Qs after frag hoist

    const int tid = threadIdx.x, wave = tid >> 6, lane = tid & 63;
    const int r16 = lane & 15, quad = lane >> 4;
    const int bh = blockIdx.x, jy = blockIdx.y;
    const int qt = (jy < 8) ? jy : 23 - jy;            // pair-balanced dispatch order
    const int b = bh >> 4, h = bh & 15;
    const size_t base  = (size_t)b * S * D + (size_t)h * DH;
    const size_t vbase = (size_t)bh * DH * S;
    const int q0 = qt * BQ;
    const int qwave = q0 + wave * 32;

    // stage Q tile (swizzled, async)
#pragma unroll
    for (int j = 0; j < 4; j++) {
        const int s = wave * 256 + j * 64 + lane;
        const int r = s >> 3;
        const int c = (s ^ r) & 7;
        gload_lds16(Q + base + (size_t)(q0 + r) * D + c * 8, &Qs[(wave * 256 + j * 64) * 8]);
    }
    __syncthreads();

    // hoist Q B-frags (loop-invariant)
    frag_ab qf[2][2];
#pragma unroll
    for (int nq = 0; nq < 2; nq++)
#pragma unroll
        for (int ks = 0; ks < 2; ks++) {
            const int row = wave * 32 + nq * 16 + r16;
            qf[nq][ks] = *(const frag_ab*)&Qs[row * 64 + (((ks * 4 + quad) ^ (row & 7)) * 8)];
        }

    float mrun[2] = {-1e30f, -1e30f}, lrun[2] = {0.f, 0.f};
    frag_cd Oacc[2][4];
#pragma unroll
    for (int mq = 0; mq < 2; mq++)
#pragma unroll
        for (int nd = 0; nd < 4; nd++) Oacc[mq][nd] = frag_cd{0.f, 0.f, 0.f, 0.f};

    const int nkt = 2 * qt + 2;
    for (int kt = 0; kt < nkt; kt++) {
        const int k0 = kt * BK;
        __syncthreads();   // prev tile consumed (and iter0: Qs frag reads drained)
#pragma unroll
        for (int j = 0; j < 2; j++) {
            const int s = wave * 128 + j * 64 + lane;
            const int r = s >> 3;
            const int c = (s ^ r) & 7;
            gload_lds16(K  + base  + (size_t)(k0 + r) * D + c * 8, &Ks[(wave * 128 + j * 64) * 8]);
            gload_lds16(Vg + vbase + (size_t)r * S + k0 + c * 8,   &Vt[(wave * 128 + j * 64) * 8]);
        }
        __syncthreads();

        if (k0 <= qwave + 31) {   // wave has unmasked keys in this tile
            frag_ab ka[4][2];
#pragma unroll
            for (int mk = 0; mk < 4; mk++) {
                const int row = mk * 16 + r16;
#pragma unroll
                for (int ks = 0; ks < 2; ks++)
                    ka[mk][ks] = *(const frag_ab*)&Ks[row * 64 + (((ks * 4 + quad) ^ (row & 7)) * 8)];
            }
            const bool domask = (k0 + BK - 1 > qwave);

#pragma unroll
            for (int nq = 0; nq < 2; nq++) {
                frag_cd Sc[4];
#pragma unroll
                for (int mk = 0; mk < 4; mk++) {
                    Sc[mk] = frag_cd{0.f, 0.f, 0.f, 0.f};
#pragma unroll
                    for (int ks = 0; ks < 2; ks++)
                        Sc[mk] = __builtin_amdgcn_mfma_f32_16x16x32_bf16(
                            ka[mk][ks], qf[nq][ks], Sc[mk], 0, 0, 0);
                }
                // S^T C-layout: col(r16)=q, row(quad*4+rg within mk-tile)=key
                const int qg = q0 + wave * 32 + nq * 16 + r16;
                float mx = -1e30f;
#pragma unroll
                for (int mk = 0; mk < 4; mk++)
#pragma unroll
                    for (int rg = 0; rg < 4; rg++) {
                        float sv = Sc[mk][rg] * KSCALE;
                        if (domask) {
                            const int keyg = k0 + mk * 16 + quad * 4 + rg;
                            sv = (keyg <= qg) ? sv : -1e30f;
                        }
                        Sc[mk][rg] = sv;
                        mx = fmaxf(mx, sv);
                    }
                mx = fmaxf(mx, __shfl_xor(mx, 16, 64));
                mx = fmaxf(mx, __shfl_xor(mx, 32, 64));
                const float mnew  = fmaxf(mrun[nq], mx);
                const float alpha = __builtin_amdgcn_exp2f(mrun[nq] - mnew);
                mrun[nq] = mnew;
                float rs = 0.f;
#pragma unroll
                for (int mk = 0; mk < 4; mk++)
#pragma unroll
                    for (int rg = 0; rg < 4; rg++) {
                        const float p = __builtin_amdgcn_exp2f(Sc[mk][rg] - mnew);
                        Sc[mk][rg] = p;
                        rs += p;
                    }
                rs += __shfl_xor(rs, 16, 64);
                rs += __shfl_xor(rs, 32, 64);
                lrun[nq] = lrun[nq] * alpha + rs;

                // packed P write: lane holds 4 consecutive keys -> b64
                const int qrow = wave * 32 + nq * 16 + r16;
#pragma unroll
                for (int mk = 0; mk < 4; mk++) {
                    __align__(8) bf16 t4[4];
#pragma unroll
                    for (int rg = 0; rg < 4; rg++) t4[rg] = __float2bfloat16(Sc[mk][rg]);
                    *(ull*)&Ps[qrow * 72 + mk * 16 + quad * 4] = *(const ull*)t4;
                }
                // rescale O for this q-band (alpha indexed by r16 -> transpose via bpermute)
#pragma unroll
                for (int rg = 0; rg < 4; rg++) {
                    const float aT = __shfl(alpha, quad * 4 + rg, 64);
#pragma unroll
                    for (int nd = 0; nd < 4; nd++) Oacc[nq][nd][rg] *= aT;
                }
            }
            // no barrier: Ps rows are wave-private, per-wave LDS in-order

            // PV: O[q][d] += P(q-major rows) x Vt(d-major rows)
            frag_ab pa[2][2], vb[4][2];
#pragma unroll
            for (int mq = 0; mq < 2; mq++) {
                const int row = wave * 32 + mq * 16 + r16;
#pragma unroll
                for (int ks = 0; ks < 2; ks++)
                    pa[mq][ks] = *(const frag_ab*)&Ps[row * 72 + ks * 32 + quad * 8];
            }
#pragma unroll
            for (int nd = 0; nd < 4; nd++) {
                const int row = nd * 16 + r16;
#pragma unroll
                for (int ks = 0; ks < 2; ks++)
                    vb[nd][ks] = *(const frag_ab*)&Vt[row * 64 + (((ks * 4 + quad) ^ (row & 7)) * 8)];
            }
#pragma unroll
            for (int mq = 0; mq < 2; mq++)
#pragma unroll
                for (int nd = 0; nd < 4; nd++)
#pragma unroll
                    for (int ks = 0; ks < 2; ks++)
                        Oacc[mq][nd] = __builtin_amdgcn_mfma_f32_16x16x32_bf16(
                            pa[mq][ks], vb[nd][ks], Oacc[mq][nd], 0, 0, 0);
        }
    }

    // epilogue: Ctx = O / l  (l indexed by r16 -> transpose via bpermute)
#pragma unroll
    for (int mq = 0; mq < 2; mq++)
#pragma unroll
        for (int rg = 0; rg < 4; rg++) {
            const float lT = __shfl(lrun[mq], quad * 4 + rg, 64);
            const float invl = 1.f / lT;
            const int qg = q0 + wave * 32 + mq * 16 + quad * 4 + rg;
#pragma unroll
            for (int nd = 0; nd < 4; nd++)
                Ctx[base + (size_t)qg * D + nd * 16 + r16] =
                    __float2bfloat16(Oacc[mq][nd][rg] * invl);
        }
}

// ---------- output projection, 64x128 tiles (512 blocks), fp32 out + bias
__global__ __launch_bounds__(256) void gemm_out64(const bf16* __restrict__ A, const bf16* __restrict__ Bt,
                                                  const float* __restrict__ bias, float* __restrict__ Out) {
    __shared__ __align__(16) bf16 As[64 * BK];
    __shared__ __align__(16) bf16 Bs[128 * BK];
    const int tid = threadIdx.x, wave = tid >> 6, lane = tid & 63;
    const int r16 = lane & 15, quad = lane >> 4;
    const int row0 = blockIdx.y * 64;
    const int col0 = blockIdx.x * 128;
    const int wm = (wave & 1) * 32, wn = (wave >> 1) * 64;

    frag_cd acc[2][4];
#pragma unroll
    for (int mt = 0; mt < 2; mt++)
#pragma unroll
        for (int nt = 0; nt < 4; nt++) acc[mt][nt] = frag_cd{0.f, 0.f, 0.f, 0.f};

    for (int k0 = 0; k0 < D; k0 += BK) {
        __syncthreads();
#pragma unroll
        for (int j = 0; j < 2; j++) {
            const int s = wave * 128 + j * 64 + lane;
            const int r = s >> 3;
            const int c = (s ^ r) & 7;
            gload_lds16(A + (size_t)(row0 + r) * D + k0 + c * 8, &As[(wave * 128 + j * 64) * 8]);
        }
#pragma unroll
        for (int j = 0; j < 4; j++) {
            const int s = wave * 256 + j * 64 + lane;
            const int r = s >> 3;
            const int c = (s ^ r) & 7;
            gload_lds16(Bt + (size_t)(col0 + r) * D + k0 + c * 8, &Bs[(wave * 256 + j * 64) * 8]);
        }
        __syncthreads();

        frag_ab af[2][2], bf[4][2];
#pragma unroll
        for (int mt = 0; mt < 2; mt++) {
            const int row = wm + mt * 16 + r16;
#pragma unroll
            for (int ks = 0; ks < 2; ks++)
                af[mt][ks] = *(const frag_ab*)&As[row * 64 + (((ks * 4 + quad) ^ (row & 7)) * 8)];
        }
#pragma unroll
        for (int nt = 0; nt < 4; nt++) {
            const int row = wn + nt * 16 + r16;
#pragma unroll
            for (int ks = 0; ks < 2; ks++)
                bf[nt][ks] = *(const frag_ab*)&Bs[row * 64 + (((ks * 4 + quad) ^ (row & 7)) * 8)];
        }
#pragma unroll
        for (int mt = 0; mt < 2; mt++)
#pragma unroll
            for (int nt = 0; nt < 4; nt++)
#pragma unroll
                for (int ks = 0; ks < 2; ks++)
                    acc[mt][nt] = __builtin_amdgcn_mfma_f32_16x16x32_bf16(
                        af[mt][ks], bf[nt][ks], acc[mt][nt], 0, 0, 0);
    }

#pragma unroll
    for (int mt = 0; mt < 2; mt++)
#pragma unroll
        for (int nt = 0; nt < 4; nt++) {
            const int col = col0 + wn + nt * 16 + r16;
            const float bv = bias[col];
#pragma unroll
            for (int rg = 0; rg < 4; rg++) {
                const int row = row0 + wm + mt * 16 + quad * 4 + rg;
                Out[(size_t)row * D + col] = acc[mt][nt][rg] + bv;
            }
        }
}

extern "C" void kernel_launch(void* const* d_in, const int* in_sizes, int n_in,
                              void* d_out, int out_size, void* d_ws, size_t ws_size,
                              hipStream_t stream) {
    const float* x  = (const float*)d_in[0];
    const float* Wq = (const float*)d_in[1];
    const float* Wk = (const float*)d_in[2];
    const float* Wv = (const float*)d_in[3];
    const float* Wo = (const float*)d_in[4];
    const float* bo = (const float*)d_in[5];
    float* out = (float*)d_out;

    bf16* xb    = (bf16*)d_ws;                 // [4096][1024]
    bf16* WqkvT = xb    + (size_t)M * D;       // [3072][1024] (WqT|WkT|WvT)
    bf16* WoT   = WqkvT + (size_t)3 * D * D;   // [1024][1024]
    bf16* Qb    = WoT   + (size_t)D * D;       // [B,S,D]
    bf16* Kb    = Qb    + (size_t)M * D;       // [B,S,D]
    bf16* Vt_g  = Kb    + (size_t)M * D;       // [32][64][2048]
    bf16* Ctxb  = Vt_g  + (size_t)M * D;       // [B,S,D]

    cvt_x<<<(M * D) / 1024, 256, 0, stream>>>(x, xb);
    cvt_wT<<<dim3(32, 32, 4), 256, 0, stream>>>(Wq, Wk, Wv, Wo,
                                                WqkvT, WqkvT + (size_t)D * D,
                                                WqkvT + (size_t)2 * D * D, WoT);
    gemm_qkv_all<<<dim3(24, 32), 256, 0, stream>>>(xb, WqkvT, Qb, Kb, Vt_g);
    attn_mfma<<<dim3(B * NH, S / BQ), 256, 0, stream>>>(Qb, Kb, Vt_g, Ctxb);
    gemm_out64<<<dim3(8, 64), 256, 0, stream>>>(Ctxb, WoT, bo, out);
}

// Round 7
// 193.593 us; speedup vs baseline: 26.1571x; 1.1415x over previous
//
#include <hip/hip_runtime.h>
#include <hip/hip_bf16.h>

#define B 2
#define S 2048
#define D 1024
#define NH 16
#define DH 64
#define M (B*S)
#define BQ 128
#define BK 64
#define KSCALE 0.18033688011112042f   // (1/sqrt(64)) * log2(e)

typedef __hip_bfloat16 bf16;
typedef __attribute__((ext_vector_type(8))) short frag_ab;   // 8 bf16
typedef __attribute__((ext_vector_type(4))) float frag_cd;   // 4 f32
typedef unsigned long long ull;

// async global->LDS, 16B/lane; LDS dest = wave-uniform base + lane*16
__device__ __forceinline__ void gload_lds16(const bf16* g, bf16* l) {
    __builtin_amdgcn_global_load_lds((const __attribute__((address_space(1))) unsigned int*)g,
                                     (__attribute__((address_space(3))) unsigned int*)l,
                                     16, 0, 0);
}

// ---------- convert x fp32 -> bf16
__global__ __launch_bounds__(256) void cvt_x(const float* __restrict__ x, bf16* __restrict__ xb) {
    const int i = (blockIdx.x * 256 + threadIdx.x) * 4;
    const float4 v = *(const float4*)(x + i);
    __align__(8) bf16 t[4] = {__float2bfloat16(v.x), __float2bfloat16(v.y),
                              __float2bfloat16(v.z), __float2bfloat16(v.w)};
    *(ull*)(xb + i) = *(const ull*)t;
}

// ---------- convert + transpose weights: T[n][k] = W[k][n]
__global__ __launch_bounds__(256) void cvt_wT(const float* __restrict__ W0, const float* __restrict__ W1,
                                              const float* __restrict__ W2, const float* __restrict__ W3,
                                              bf16* __restrict__ T0, bf16* __restrict__ T1,
                                              bf16* __restrict__ T2, bf16* __restrict__ T3) {
    const float* src; bf16* dst;
    switch (blockIdx.z) {
        case 0: src = W0; dst = T0; break;
        case 1: src = W1; dst = T1; break;
        case 2: src = W2; dst = T2; break;
        default: src = W3; dst = T3; break;
    }
    __shared__ float t[32][33];
    const int tx = threadIdx.x & 31, ty = threadIdx.x >> 5;
    const int c0 = blockIdx.x * 32, r0 = blockIdx.y * 32;
#pragma unroll
    for (int i = 0; i < 4; i++)
        t[ty + 8 * i][tx] = src[(size_t)(r0 + ty + 8 * i) * D + c0 + tx];
    __syncthreads();
#pragma unroll
    for (int i = 0; i < 4; i++)
        dst[(size_t)(c0 + ty + 8 * i) * D + r0 + tx] = __float2bfloat16(t[tx][ty + 8 * i]);
}

// ---------- fused QKV GEMM: C = xb @ [WqT|WkT|WvT]^T, 128x128 tiles, grid (24,32).
// Q/K thirds stored row-major; V third stored TRANSPOSED per head: Vt[bh][d][s].
__global__ __launch_bounds__(256) void gemm_qkv_all(const bf16* __restrict__ A, const bf16* __restrict__ Bt,
                                                    bf16* __restrict__ Qb, bf16* __restrict__ Kb,
                                                    bf16* __restrict__ Vt_g) {
    __shared__ __align__(16) bf16 As[128 * BK];
    __shared__ __align__(16) bf16 Bs[128 * BK];
    const int tid = threadIdx.x, wave = tid >> 6, lane = tid & 63;
    const int r16 = lane & 15, quad = lane >> 4;
    const int row0 = blockIdx.y * 128;
    const int col0 = blockIdx.x * 128;
    const int wm = (wave & 1) * 64, wn = (wave >> 1) * 64;

    frag_cd acc[4][4];
#pragma unroll
    for (int mt = 0; mt < 4; mt++)
#pragma unroll
        for (int nt = 0; nt < 4; nt++) acc[mt][nt] = frag_cd{0.f, 0.f, 0.f, 0.f};

    for (int k0 = 0; k0 < D; k0 += BK) {
        __syncthreads();
#pragma unroll
        for (int j = 0; j < 4; j++) {
            const int s = wave * 256 + j * 64 + lane;
            const int r = s >> 3;
            const int c = (s ^ r) & 7;
            gload_lds16(A  + (size_t)(row0 + r) * D + k0 + c * 8, &As[(wave * 256 + j * 64) * 8]);
            gload_lds16(Bt + (size_t)(col0 + r) * D + k0 + c * 8, &Bs[(wave * 256 + j * 64) * 8]);
        }
        __syncthreads();

        frag_ab af[4][2], bf[4][2];
#pragma unroll
        for (int mt = 0; mt < 4; mt++) {
            const int row = wm + mt * 16 + r16;
#pragma unroll
            for (int ks = 0; ks < 2; ks++)
                af[mt][ks] = *(const frag_ab*)&As[row * 64 + (((ks * 4 + quad) ^ (row & 7)) * 8)];
        }
#pragma unroll
        for (int nt = 0; nt < 4; nt++) {
            const int row = wn + nt * 16 + r16;
#pragma unroll
            for (int ks = 0; ks < 2; ks++)
                bf[nt][ks] = *(const frag_ab*)&Bs[row * 64 + (((ks * 4 + quad) ^ (row & 7)) * 8)];
        }
#pragma unroll
        for (int mt = 0; mt < 4; mt++)
#pragma unroll
            for (int nt = 0; nt < 4; nt++)
#pragma unroll
                for (int ks = 0; ks < 2; ks++)
                    acc[mt][nt] = __builtin_amdgcn_mfma_f32_16x16x32_bf16(
                        af[mt][ks], bf[nt][ks], acc[mt][nt], 0, 0, 0);
    }

    const int third = col0 >> 10;
    if (third < 2) {
        bf16* Out = (third == 0) ? Qb : Kb;
#pragma unroll
        for (int mt = 0; mt < 4; mt++)
#pragma unroll
            for (int nt = 0; nt < 4; nt++) {
                const int cl = (col0 + wn + nt * 16 + r16) & 1023;
#pragma unroll
                for (int rg = 0; rg < 4; rg++) {
                    const int row = row0 + wm + mt * 16 + quad * 4 + rg;
                    Out[(size_t)row * D + cl] = __float2bfloat16(acc[mt][nt][rg]);
                }
            }
    } else {
        const int bb = row0 >> 11;
        const int sb0 = (row0 & 2047) + wm;
#pragma unroll
        for (int mt = 0; mt < 4; mt++)
#pragma unroll
            for (int nt = 0; nt < 4; nt++) {
                const int c  = (col0 + wn + nt * 16 + r16) - 2048;
                const int hh = c >> 6, dl = c & 63;
                const int sb = sb0 + mt * 16 + quad * 4;
                __align__(8) bf16 t4[4];
#pragma unroll
                for (int rg = 0; rg < 4; rg++) t4[rg] = __float2bfloat16(acc[mt][nt][rg]);
                *(ull*)(Vt_g + (((size_t)bb * 16 + hh) * 64 + dl) * S + sb) = *(const ull*)t4;
            }
    }
}

// ---------- Flash attention, S^T formulation, single-barrier double-buffered K-loop.
// Q,K bf16 [B,S,D]; Vg = Vt[bh][d][s]; Ctx bf16 [B,S,D].
__global__ __launch_bounds__(256) void attn_mfma(const bf16* __restrict__ Q,
                                                 const bf16* __restrict__ K,
                                                 const bf16* __restrict__ Vg,
                                                 bf16* __restrict__ Ctx) {
    __shared__ __align__(16) bf16 Ks[2][BK * DH];   // 8 KB x2, XOR-8 swizzled rows=key
    __shared__ __align__(16) bf16 Vt[2][BK * DH];   // 8 KB x2, rows=dim cols=key
    __shared__ __align__(16) bf16 Qs[BQ * DH];      // 16 KB staging; overlaid by Ps
    bf16* Ps = Qs;   // [128][64], granule(4-elem)-XOR swizzled; rows wave-private

    const int tid = threadIdx.x, wave = tid >> 6, lane = tid & 63;
    const int r16 = lane & 15, quad = lane >> 4;
    const int bh = blockIdx.x, jy = blockIdx.y;
    const int qt = (jy < 8) ? jy : 23 - jy;
    const int b = bh >> 4, h = bh & 15;
    const size_t base  = (size_t)b * S * D + (size_t)h * DH;
    const size_t vbase = (size_t)bh * DH * S;
    const int q0 = qt * BQ;
    const int qwave = q0 + wave * 32;
    const int nkt = 2 * qt + 2;

    // ---- prologue: async-stage Q tile and K/V tile 0 (buf 0)
#pragma unroll
    for (int j = 0; j < 4; j++) {
        const int s = wave * 256 + j * 64 + lane;
        const int r = s >> 3;
        const int c = (s ^ r) & 7;
        gload_lds16(Q + base + (size_t)(q0 + r) * D + c * 8, &Qs[(wave * 256 + j * 64) * 8]);
    }
#pragma unroll
    for (int j = 0; j < 2; j++) {
        const int s = wave * 128 + j * 64 + lane;
        const int r = s >> 3;
        const int c = (s ^ r) & 7;
        gload_lds16(K  + base  + (size_t)r * D + c * 8, &Ks[0][(wave * 128 + j * 64) * 8]);
        gload_lds16(Vg + vbase + (size_t)r * S + c * 8, &Vt[0][(wave * 128 + j * 64) * 8]);
    }
    __syncthreads();

    // hoist Q B-frags (registers from here on; Qs LDS free to reuse as Ps)
    frag_ab qf[2][2];
#pragma unroll
    for (int nq = 0; nq < 2; nq++)
#pragma unroll
        for (int ks = 0; ks < 2; ks++) {
            const int row = wave * 32 + nq * 16 + r16;
            qf[nq][ks] = *(const frag_ab*)&Qs[row * 64 + (((ks * 4 + quad) ^ (row & 7)) * 8)];
        }

    float mrun[2] = {-1e30f, -1e30f}, lrun[2] = {0.f, 0.f};
    frag_cd Oacc[2][4];
#pragma unroll
    for (int mq = 0; mq < 2; mq++)
#pragma unroll
        for (int nd = 0; nd < 4; nd++) Oacc[mq][nd] = frag_cd{0.f, 0.f, 0.f, 0.f};

    for (int kt = 0; kt < nkt; kt++) {
        const int k0  = kt * BK;
        const int cur = kt & 1;

        // ---- prefetch next K/V tile into alternate buffer (hidden under compute)
        if (kt + 1 < nkt) {
            const int kn = k0 + BK;
#pragma unroll
            for (int j = 0; j < 2; j++) {
                const int s = wave * 128 + j * 64 + lane;
                const int r = s >> 3;
                const int c = (s ^ r) & 7;
                gload_lds16(K  + base  + (size_t)(kn + r) * D + c * 8,
                            &Ks[cur ^ 1][(wave * 128 + j * 64) * 8]);
                gload_lds16(Vg + vbase + (size_t)r * S + kn + c * 8,
                            &Vt[cur ^ 1][(wave * 128 + j * 64) * 8]);
            }
        }

        if (k0 <= qwave + 31) {   // wave has unmasked keys in this tile
            frag_ab ka[4][2];
#pragma unroll
            for (int mk = 0; mk < 4; mk++) {
                const int row = mk * 16 + r16;
#pragma unroll
                for (int ks = 0; ks < 2; ks++)
                    ka[mk][ks] = *(const frag_ab*)&Ks[cur][row * 64 + (((ks * 4 + quad) ^ (row & 7)) * 8)];
            }
            const bool domask = (k0 + BK - 1 > qwave);

#pragma unroll
            for (int nq = 0; nq < 2; nq++) {
                frag_cd Sc[4];
#pragma unroll
                for (int mk = 0; mk < 4; mk++) {
                    Sc[mk] = frag_cd{0.f, 0.f, 0.f, 0.f};
#pragma unroll
                    for (int ks = 0; ks < 2; ks++)
                        Sc[mk] = __builtin_amdgcn_mfma_f32_16x16x32_bf16(
                            ka[mk][ks], qf[nq][ks], Sc[mk], 0, 0, 0);
                }
                // S^T C-layout: col(r16)=q, row(quad*4+rg in mk-tile)=key
                const int qg = q0 + wave * 32 + nq * 16 + r16;
                float mx = -1e30f;
#pragma unroll
                for (int mk = 0; mk < 4; mk++)
#pragma unroll
                    for (int rg = 0; rg < 4; rg++) {
                        float sv = Sc[mk][rg] * KSCALE;
                        if (domask) {
                            const int keyg = k0 + mk * 16 + quad * 4 + rg;
                            sv = (keyg <= qg) ? sv : -1e30f;
                        }
                        Sc[mk][rg] = sv;
                        mx = fmaxf(mx, sv);
                    }
                mx = fmaxf(mx, __shfl_xor(mx, 16, 64));
                mx = fmaxf(mx, __shfl_xor(mx, 32, 64));
                const float mnew  = fmaxf(mrun[nq], mx);
                const float alpha = __builtin_amdgcn_exp2f(mrun[nq] - mnew);
                mrun[nq] = mnew;
                float rs = 0.f;
#pragma unroll
                for (int mk = 0; mk < 4; mk++)
#pragma unroll
                    for (int rg = 0; rg < 4; rg++) {
                        const float p = __builtin_amdgcn_exp2f(Sc[mk][rg] - mnew);
                        Sc[mk][rg] = p;
                        rs += p;
                    }
                rs += __shfl_xor(rs, 16, 64);
                rs += __shfl_xor(rs, 32, 64);
                lrun[nq] = lrun[nq] * alpha + rs;

                // packed P write: 4 consecutive keys/lane, granule-XOR swizzle (b64 floor)
                const int qrow = wave * 32 + nq * 16 + r16;
#pragma unroll
                for (int mk = 0; mk < 4; mk++) {
                    __align__(8) bf16 t4[4];
#pragma unroll
                    for (int rg = 0; rg < 4; rg++) t4[rg] = __float2bfloat16(Sc[mk][rg]);
                    const int g = (mk * 4 + quad) ^ r16;
                    *(ull*)&Ps[qrow * 64 + g * 4] = *(const ull*)t4;
                }
                // rescale O (alpha indexed by r16 -> transpose via shfl)
#pragma unroll
                for (int rg = 0; rg < 4; rg++) {
                    const float aT = __shfl(alpha, quad * 4 + rg, 64);
#pragma unroll
                    for (int nd = 0; nd < 4; nd++) Oacc[nq][nd][rg] *= aT;
                }
            }
            // no barrier: Ps rows wave-private; per-wave LDS ops are in-order

            // PV: O[q][d] += P(q rows) x Vt(d rows)
            frag_ab pa[2][2], vb[4][2];
#pragma unroll
            for (int mq = 0; mq < 2; mq++) {
                const int row = wave * 32 + mq * 16 + r16;
#pragma unroll
                for (int ks = 0; ks < 2; ks++) {
                    const int gb = ks * 8 + quad * 2;
                    union { ull u[2]; frag_ab f; } t;
                    t.u[0] = *(const ull*)&Ps[row * 64 + ((gb    ) ^ r16) * 4];
                    t.u[1] = *(const ull*)&Ps[row * 64 + ((gb + 1) ^ r16) * 4];
                    pa[mq][ks] = t.f;
                }
            }
#pragma unroll
            for (int nd = 0; nd < 4; nd++) {
                const int row = nd * 16 + r16;
#pragma unroll
                for (int ks = 0; ks < 2; ks++)
                    vb[nd][ks] = *(const frag_ab*)&Vt[cur][row * 64 + (((ks * 4 + quad) ^ (row & 7)) * 8)];
            }
#pragma unroll
            for (int mq = 0; mq < 2; mq++)
#pragma unroll
                for (int nd = 0; nd < 4; nd++)
#pragma unroll
                    for (int ks = 0; ks < 2; ks++)
                        Oacc[mq][nd] = __builtin_amdgcn_mfma_f32_16x16x32_bf16(
                            pa[mq][ks], vb[nd][ks], Oacc[mq][nd], 0, 0, 0);
        }

        __syncthreads();   // joins: prefetch (vmcnt) complete + all waves done with cur bufs
    }

    // epilogue: Ctx = O / l  (l indexed by r16 -> transpose via shfl)
#pragma unroll
    for (int mq = 0; mq < 2; mq++)
#pragma unroll
        for (int rg = 0; rg < 4; rg++) {
            const float lT = __shfl(lrun[mq], quad * 4 + rg, 64);
            const float invl = 1.f / lT;
            const int qg = q0 + wave * 32 + mq * 16 + quad * 4 + rg;
#pragma unroll
            for (int nd = 0; nd < 4; nd++)
                Ctx[base + (size_t)qg * D + nd * 16 + r16] =
                    __float2bfloat16(Oacc[mq][nd][rg] * invl);
        }
}

// ---------- output projection, 64x128 tiles (512 blocks), fp32 out + bias
__global__ __launch_bounds__(256) void gemm_out64(const bf16* __restrict__ A, const bf16* __restrict__ Bt,
                                                  const float* __restrict__ bias, float* __restrict__ Out) {
    __shared__ __align__(16) bf16 As[64 * BK];
    __shared__ __align__(16) bf16 Bs[128 * BK];
    const int tid = threadIdx.x, wave = tid >> 6, lane = tid & 63;
    const int r16 = lane & 15, quad = lane >> 4;
    const int row0 = blockIdx.y * 64;
    const int col0 = blockIdx.x * 128;
    const int wm = (wave & 1) * 32, wn = (wave >> 1) * 64;

    frag_cd acc[2][4];
#pragma unroll
    for (int mt = 0; mt < 2; mt++)
#pragma unroll
        for (int nt = 0; nt < 4; nt++) acc[mt][nt] = frag_cd{0.f, 0.f, 0.f, 0.f};

    for (int k0 = 0; k0 < D; k0 += BK) {
        __syncthreads();
#pragma unroll
        for (int j = 0; j < 2; j++) {
            const int s = wave * 128 + j * 64 + lane;
            const int r = s >> 3;
            const int c = (s ^ r) & 7;
            gload_lds16(A + (size_t)(row0 + r) * D + k0 + c * 8, &As[(wave * 128 + j * 64) * 8]);
        }
#pragma unroll
        for (int j = 0; j < 4; j++) {
            const int s = wave * 256 + j * 64 + lane;
            const int r = s >> 3;
            const int c = (s ^ r) & 7;
            gload_lds16(Bt + (size_t)(col0 + r) * D + k0 + c * 8, &Bs[(wave * 256 + j * 64) * 8]);
        }
        __syncthreads();

        frag_ab af[2][2], bf[4][2];
#pragma unroll
        for (int mt = 0; mt < 2; mt++) {
            const int row = wm + mt * 16 + r16;
#pragma unroll
            for (int ks = 0; ks < 2; ks++)
                af[mt][ks] = *(const frag_ab*)&As[row * 64 + (((ks * 4 + quad) ^ (row & 7)) * 8)];
        }
#pragma unroll
        for (int nt = 0; nt < 4; nt++) {
            const int row = wn + nt * 16 + r16;
#pragma unroll
            for (int ks = 0; ks < 2; ks++)
                bf[nt][ks] = *(const frag_ab*)&Bs[row * 64 + (((ks * 4 + quad) ^ (row & 7)) * 8)];
        }
#pragma unroll
        for (int mt = 0; mt < 2; mt++)
#pragma unroll
            for (int nt = 0; nt < 4; nt++)
#pragma unroll
                for (int ks = 0; ks < 2; ks++)
                    acc[mt][nt] = __builtin_amdgcn_mfma_f32_16x16x32_bf16(
                        af[mt][ks], bf[nt][ks], acc[mt][nt], 0, 0, 0);
    }

#pragma unroll
    for (int mt = 0; mt < 2; mt++)
#pragma unroll
        for (int nt = 0; nt < 4; nt++) {
            const int col = col0 + wn + nt * 16 + r16;
            const float bv = bias[col];
#pragma unroll
            for (int rg = 0; rg < 4; rg++) {
                const int row = row0 + wm + mt * 16 + quad * 4 + rg;
                Out[(size_t)row * D + col] = acc[mt][nt][rg] + bv;
            }
        }
}

extern "C" void kernel_launch(void* const* d_in, const int* in_sizes, int n_in,
                              void* d_out, int out_size, void* d_ws, size_t ws_size,
                              hipStream_t stream) {
    const float* x  = (const float*)d_in[0];
    const float* Wq = (const float*)d_in[1];
    const float* Wk = (const float*)d_in[2];
    const float* Wv = (const float*)d_in[3];
    const float* Wo = (const float*)d_in[4];
    const float* bo = (const float*)d_in[5];
    float* out = (float*)d_out;

    bf16* xb    = (bf16*)d_ws;                 // [4096][1024]
    bf16* WqkvT = xb    + (size_t)M * D;       // [3072][1024] (WqT|WkT|WvT)
    bf16* WoT   = WqkvT + (size_t)3 * D * D;   // [1024][1024]
    bf16* Qb    = WoT   + (size_t)D * D;       // [B,S,D]
    bf16* Kb    = Qb    + (size_t)M * D;       // [B,S,D]
    bf16* Vt_g  = Kb    + (size_t)M * D;       // [32][64][2048]
    bf16* Ctxb  = Vt_g  + (size_t)M * D;       // [B,S,D]

    cvt_x<<<(M * D) / 1024, 256, 0, stream>>>(x, xb);
    cvt_wT<<<dim3(32, 32, 4), 256, 0, stream>>>(Wq, Wk, Wv, Wo,
                                                WqkvT, WqkvT + (size_t)D * D,
                                                WqkvT + (size_t)2 * D * D, WoT);
    gemm_qkv_all<<<dim3(24, 32), 256, 0, stream>>>(xb, WqkvT, Qb, Kb, Vt_g);
    attn_mfma<<<dim3(B * NH, S / BQ), 256, 0, stream>>>(Qb, Kb, Vt_g, Ctxb);
    gemm_out64<<<dim3(8, 64), 256, 0, stream>>>(Ctxb, WoT, bo, out);
}

// Round 8
// 187.459 us; speedup vs baseline: 27.0130x; 1.0327x over previous
//
#include <hip/hip_runtime.h>
#include <hip/hip_bf16.h>

#define B 2
#define S 2048
#define D 1024
#define NH 16
#define DH 64
#define M (B*S)
#define BQ 128
#define BK 64
#define KSCALE 0.18033688011112042f   // (1/sqrt(64)) * log2(e)

typedef __hip_bfloat16 bf16;
typedef __attribute__((ext_vector_type(8))) short frag_ab;   // 8 bf16
typedef __attribute__((ext_vector_type(4))) float frag_cd;   // 4 f32
typedef unsigned long long ull;

// async global->LDS, 16B/lane; LDS dest = wave-uniform base + lane*16
__device__ __forceinline__ void gload_lds16(const bf16* g, bf16* l) {
    __builtin_amdgcn_global_load_lds((const __attribute__((address_space(1))) unsigned int*)g,
                                     (__attribute__((address_space(3))) unsigned int*)l,
                                     16, 0, 0);
}

// ---------- convert x fp32 -> bf16
__global__ __launch_bounds__(256) void cvt_x(const float* __restrict__ x, bf16* __restrict__ xb) {
    const int i = (blockIdx.x * 256 + threadIdx.x) * 4;
    const float4 v = *(const float4*)(x + i);
    __align__(8) bf16 t[4] = {__float2bfloat16(v.x), __float2bfloat16(v.y),
                              __float2bfloat16(v.z), __float2bfloat16(v.w)};
    *(ull*)(xb + i) = *(const ull*)t;
}

// ---------- convert + transpose weights: T[n][k] = W[k][n]
__global__ __launch_bounds__(256) void cvt_wT(const float* __restrict__ W0, const float* __restrict__ W1,
                                              const float* __restrict__ W2, const float* __restrict__ W3,
                                              bf16* __restrict__ T0, bf16* __restrict__ T1,
                                              bf16* __restrict__ T2, bf16* __restrict__ T3) {
    const float* src; bf16* dst;
    switch (blockIdx.z) {
        case 0: src = W0; dst = T0; break;
        case 1: src = W1; dst = T1; break;
        case 2: src = W2; dst = T2; break;
        default: src = W3; dst = T3; break;
    }
    __shared__ float t[32][33];
    const int tx = threadIdx.x & 31, ty = threadIdx.x >> 5;
    const int c0 = blockIdx.x * 32, r0 = blockIdx.y * 32;
#pragma unroll
    for (int i = 0; i < 4; i++)
        t[ty + 8 * i][tx] = src[(size_t)(r0 + ty + 8 * i) * D + c0 + tx];
    __syncthreads();
#pragma unroll
    for (int i = 0; i < 4; i++)
        dst[(size_t)(c0 + ty + 8 * i) * D + r0 + tx] = __float2bfloat16(t[tx][ty + 8 * i]);
}

// ---------- fused QKV GEMM: C = xb @ [WqT|WkT|WvT]^T, 128x128 tiles, grid (24,32).
// Q/K thirds stored row-major; V third stored TRANSPOSED per head: Vt[bh][d][s].
__global__ __launch_bounds__(256) void gemm_qkv_all(const bf16* __restrict__ A, const bf16* __restrict__ Bt,
                                                    bf16* __restrict__ Qb, bf16* __restrict__ Kb,
                                                    bf16* __restrict__ Vt_g) {
    __shared__ __align__(16) bf16 As[128 * BK];
    __shared__ __align__(16) bf16 Bs[128 * BK];
    const int tid = threadIdx.x, wave = tid >> 6, lane = tid & 63;
    const int r16 = lane & 15, quad = lane >> 4;
    const int row0 = blockIdx.y * 128;
    const int col0 = blockIdx.x * 128;
    const int wm = (wave & 1) * 64, wn = (wave >> 1) * 64;

    frag_cd acc[4][4];
#pragma unroll
    for (int mt = 0; mt < 4; mt++)
#pragma unroll
        for (int nt = 0; nt < 4; nt++) acc[mt][nt] = frag_cd{0.f, 0.f, 0.f, 0.f};

    for (int k0 = 0; k0 < D; k0 += BK) {
        __syncthreads();
#pragma unroll
        for (int j = 0; j < 4; j++) {
            const int s = wave * 256 + j * 64 + lane;
            const int r = s >> 3;
            const int c = (s ^ r) & 7;
            gload_lds16(A  + (size_t)(row0 + r) * D + k0 + c * 8, &As[(wave * 256 + j * 64) * 8]);
            gload_lds16(Bt + (size_t)(col0 + r) * D + k0 + c * 8, &Bs[(wave * 256 + j * 64) * 8]);
        }
        __syncthreads();

        frag_ab af[4][2], bf[4][2];
#pragma unroll
        for (int mt = 0; mt < 4; mt++) {
            const int row = wm + mt * 16 + r16;
#pragma unroll
            for (int ks = 0; ks < 2; ks++)
                af[mt][ks] = *(const frag_ab*)&As[row * 64 + (((ks * 4 + quad) ^ (row & 7)) * 8)];
        }
#pragma unroll
        for (int nt = 0; nt < 4; nt++) {
            const int row = wn + nt * 16 + r16;
#pragma unroll
            for (int ks = 0; ks < 2; ks++)
                bf[nt][ks] = *(const frag_ab*)&Bs[row * 64 + (((ks * 4 + quad) ^ (row & 7)) * 8)];
        }
#pragma unroll
        for (int mt = 0; mt < 4; mt++)
#pragma unroll
            for (int nt = 0; nt < 4; nt++)
#pragma unroll
                for (int ks = 0; ks < 2; ks++)
                    acc[mt][nt] = __builtin_amdgcn_mfma_f32_16x16x32_bf16(
                        af[mt][ks], bf[nt][ks], acc[mt][nt], 0, 0, 0);
    }

    const int third = col0 >> 10;
    if (third < 2) {
        bf16* Out = (third == 0) ? Qb : Kb;
#pragma unroll
        for (int mt = 0; mt < 4; mt++)
#pragma unroll
            for (int nt = 0; nt < 4; nt++) {
                const int cl = (col0 + wn + nt * 16 + r16) & 1023;
#pragma unroll
                for (int rg = 0; rg < 4; rg++) {
                    const int row = row0 + wm + mt * 16 + quad * 4 + rg;
                    Out[(size_t)row * D + cl] = __float2bfloat16(acc[mt][nt][rg]);
                }
            }
    } else {
        const int bb = row0 >> 11;
        const int sb0 = (row0 & 2047) + wm;
#pragma unroll
        for (int mt = 0; mt < 4; mt++)
#pragma unroll
            for (int nt = 0; nt < 4; nt++) {
                const int c  = (col0 + wn + nt * 16 + r16) - 2048;
                const int hh = c >> 6, dl = c & 63;
                const int sb = sb0 + mt * 16 + quad * 4;
                __align__(8) bf16 t4[4];
#pragma unroll
                for (int rg = 0; rg < 4; rg++) t4[rg] = __float2bfloat16(acc[mt][nt][rg]);
                *(ull*)(Vt_g + (((size_t)bb * 16 + hh) * 64 + dl) * S + sb) = *(const ull*)t4;
            }
    }
}

// ---------- Flash attention, S^T formulation + TRANSPOSED O accumulation.
// Q,K bf16 [B,S,D]; Vg = Vt[bh][d][s]; Ctx bf16 [B,S,D].
// O^T C-layout has col=q=r16 — alpha/l apply per-lane with NO shuffles.
__global__ __launch_bounds__(256) void attn_mfma(const bf16* __restrict__ Q,
                                                 const bf16* __restrict__ K,
                                                 const bf16* __restrict__ Vg,
                                                 bf16* __restrict__ Ctx) {
    __shared__ __align__(16) bf16 Ks[2][BK * DH];   // 8 KB x2, XOR-8 swizzled rows=key
    __shared__ __align__(16) bf16 Vt[2][BK * DH];   // 8 KB x2, rows=dim cols=key
    __shared__ __align__(16) bf16 Qs[BQ * DH];      // 16 KB staging; overlaid by Ps
    bf16* Ps = Qs;   // [128][64], granule(4-elem)-XOR swizzled; rows wave-private

    const int tid = threadIdx.x, wave = tid >> 6, lane = tid & 63;
    const int r16 = lane & 15, quad = lane >> 4;
    const int bh = blockIdx.x, jy = blockIdx.y;
    const int qt = (jy < 8) ? jy : 23 - jy;
    const int b = bh >> 4, h = bh & 15;
    const size_t base  = (size_t)b * S * D + (size_t)h * DH;
    const size_t vbase = (size_t)bh * DH * S;
    const int q0 = qt * BQ;
    const int qwave = q0 + wave * 32;
    const int nkt = 2 * qt + 2;

    // ---- prologue: async-stage Q tile and K/V tile 0 (buf 0)
#pragma unroll
    for (int j = 0; j < 4; j++) {
        const int s = wave * 256 + j * 64 + lane;
        const int r = s >> 3;
        const int c = (s ^ r) & 7;
        gload_lds16(Q + base + (size_t)(q0 + r) * D + c * 8, &Qs[(wave * 256 + j * 64) * 8]);
    }
#pragma unroll
    for (int j = 0; j < 2; j++) {
        const int s = wave * 128 + j * 64 + lane;
        const int r = s >> 3;
        const int c = (s ^ r) & 7;
        gload_lds16(K  + base  + (size_t)r * D + c * 8, &Ks[0][(wave * 128 + j * 64) * 8]);
        gload_lds16(Vg + vbase + (size_t)r * S + c * 8, &Vt[0][(wave * 128 + j * 64) * 8]);
    }
    __syncthreads();

    // hoist Q B-frags (registers from here on; Qs LDS free to reuse as Ps)
    frag_ab qf[2][2];
#pragma unroll
    for (int nq = 0; nq < 2; nq++)
#pragma unroll
        for (int ks = 0; ks < 2; ks++) {
            const int row = wave * 32 + nq * 16 + r16;
            qf[nq][ks] = *(const frag_ab*)&Qs[row * 64 + (((ks * 4 + quad) ^ (row & 7)) * 8)];
        }

    float mrun[2] = {-1e30f, -1e30f}, lrun[2] = {0.f, 0.f};
    frag_cd Oacc[2][4];   // [q-band][d-tile] = O^T tile: row=d(quad*4+rg), col=q(r16)
#pragma unroll
    for (int mq = 0; mq < 2; mq++)
#pragma unroll
        for (int nd = 0; nd < 4; nd++) Oacc[mq][nd] = frag_cd{0.f, 0.f, 0.f, 0.f};

    for (int kt = 0; kt < nkt; kt++) {
        const int k0  = kt * BK;
        const int cur = kt & 1;

        // ---- prefetch next K/V tile into alternate buffer (hidden under compute)
        if (kt + 1 < nkt) {
            const int kn = k0 + BK;
#pragma unroll
            for (int j = 0; j < 2; j++) {
                const int s = wave * 128 + j * 64 + lane;
                const int r = s >> 3;
                const int c = (s ^ r) & 7;
                gload_lds16(K  + base  + (size_t)(kn + r) * D + c * 8,
                            &Ks[cur ^ 1][(wave * 128 + j * 64) * 8]);
                gload_lds16(Vg + vbase + (size_t)r * S + kn + c * 8,
                            &Vt[cur ^ 1][(wave * 128 + j * 64) * 8]);
            }
        }

        if (k0 <= qwave + 31) {   // wave has unmasked keys in this tile
            frag_ab ka[4][2];
#pragma unroll
            for (int mk = 0; mk < 4; mk++) {
                const int row = mk * 16 + r16;
#pragma unroll
                for (int ks = 0; ks < 2; ks++)
                    ka[mk][ks] = *(const frag_ab*)&Ks[cur][row * 64 + (((ks * 4 + quad) ^ (row & 7)) * 8)];
            }
            const bool domask = (k0 + BK - 1 > qwave);

#pragma unroll
            for (int nq = 0; nq < 2; nq++) {
                frag_cd Sc[4];
#pragma unroll
                for (int mk = 0; mk < 4; mk++) {
                    Sc[mk] = frag_cd{0.f, 0.f, 0.f, 0.f};
#pragma unroll
                    for (int ks = 0; ks < 2; ks++)
                        Sc[mk] = __builtin_amdgcn_mfma_f32_16x16x32_bf16(
                            ka[mk][ks], qf[nq][ks], Sc[mk], 0, 0, 0);
                }
                // S^T C-layout: col(r16)=q, row(quad*4+rg in mk-tile)=key
                const int qg = q0 + wave * 32 + nq * 16 + r16;
                float mx = -1e30f;
#pragma unroll
                for (int mk = 0; mk < 4; mk++)
#pragma unroll
                    for (int rg = 0; rg < 4; rg++) {
                        float sv = Sc[mk][rg] * KSCALE;
                        if (domask) {
                            const int keyg = k0 + mk * 16 + quad * 4 + rg;
                            sv = (keyg <= qg) ? sv : -1e30f;
                        }
                        Sc[mk][rg] = sv;
                        mx = fmaxf(mx, sv);
                    }
                mx = fmaxf(mx, __shfl_xor(mx, 16, 64));
                mx = fmaxf(mx, __shfl_xor(mx, 32, 64));
                const float mnew  = fmaxf(mrun[nq], mx);
                const float alpha = __builtin_amdgcn_exp2f(mrun[nq] - mnew);
                mrun[nq] = mnew;
                float rs = 0.f;
#pragma unroll
                for (int mk = 0; mk < 4; mk++)
#pragma unroll
                    for (int rg = 0; rg < 4; rg++) {
                        const float p = __builtin_amdgcn_exp2f(Sc[mk][rg] - mnew);
                        Sc[mk][rg] = p;
                        rs += p;
                    }
                rs += __shfl_xor(rs, 16, 64);
                rs += __shfl_xor(rs, 32, 64);
                lrun[nq] = lrun[nq] * alpha + rs;

                // packed P write: 4 consecutive keys/lane, granule-XOR swizzle (b64 floor)
                const int qrow = wave * 32 + nq * 16 + r16;
#pragma unroll
                for (int mk = 0; mk < 4; mk++) {
                    __align__(8) bf16 t4[4];
#pragma unroll
                    for (int rg = 0; rg < 4; rg++) t4[rg] = __float2bfloat16(Sc[mk][rg]);
                    const int g = (mk * 4 + quad) ^ r16;
                    *(ull*)&Ps[qrow * 64 + g * 4] = *(const ull*)t4;
                }
                // rescale O^T: col=q=r16 matches alpha's index — direct multiply
#pragma unroll
                for (int nd = 0; nd < 4; nd++)
#pragma unroll
                    for (int rg = 0; rg < 4; rg++) Oacc[nq][nd][rg] *= alpha;
            }
            // no barrier: Ps rows wave-private; per-wave LDS ops are in-order

            // PV (transposed): O^T[d][q] += Vt(d rows) x P(q rows)
            frag_ab pa[2][2], vb[4][2];
#pragma unroll
            for (int mq = 0; mq < 2; mq++) {
                const int row = wave * 32 + mq * 16 + r16;
#pragma unroll
                for (int ks = 0; ks < 2; ks++) {
                    const int gb = ks * 8 + quad * 2;
                    union { ull u[2]; frag_ab f; } t;
                    t.u[0] = *(const ull*)&Ps[row * 64 + ((gb    ) ^ r16) * 4];
                    t.u[1] = *(const ull*)&Ps[row * 64 + ((gb + 1) ^ r16) * 4];
                    pa[mq][ks] = t.f;
                }
            }
#pragma unroll
            for (int nd = 0; nd < 4; nd++) {
                const int row = nd * 16 + r16;
#pragma unroll
                for (int ks = 0; ks < 2; ks++)
                    vb[nd][ks] = *(const frag_ab*)&Vt[cur][row * 64 + (((ks * 4 + quad) ^ (row & 7)) * 8)];
            }
#pragma unroll
            for (int mq = 0; mq < 2; mq++)
#pragma unroll
                for (int nd = 0; nd < 4; nd++)
#pragma unroll
                    for (int ks = 0; ks < 2; ks++)
                        Oacc[mq][nd] = __builtin_amdgcn_mfma_f32_16x16x32_bf16(
                            vb[nd][ks], pa[mq][ks], Oacc[mq][nd], 0, 0, 0);
        }

        __syncthreads();   // joins: prefetch (vmcnt) complete + all waves done with cur bufs
    }

    // epilogue: Ctx[q][d] = O^T[d][q] / l — lane holds 4 consecutive d -> packed b64
#pragma unroll
    for (int mq = 0; mq < 2; mq++) {
        const float invl = 1.f / lrun[mq];
        const int qg = q0 + wave * 32 + mq * 16 + r16;
#pragma unroll
        for (int nd = 0; nd < 4; nd++) {
            __align__(8) bf16 t4[4];
#pragma unroll
            for (int rg = 0; rg < 4; rg++)
                t4[rg] = __float2bfloat16(Oacc[mq][nd][rg] * invl);
            *(ull*)(Ctx + base + (size_t)qg * D + nd * 16 + quad * 4) = *(const ull*)t4;
        }
    }
}

// ---------- output projection, 64x128 tiles (512 blocks), fp32 out + bias
__global__ __launch_bounds__(256) void gemm_out64(const bf16* __restrict__ A, const bf16* __restrict__ Bt,
                                                  const float* __restrict__ bias, float* __restrict__ Out) {
    __shared__ __align__(16) bf16 As[64 * BK];
    __shared__ __align__(16) bf16 Bs[128 * BK];
    const int tid = threadIdx.x, wave = tid >> 6, lane = tid & 63;
    const int r16 = lane & 15, quad = lane >> 4;
    const int row0 = blockIdx.y * 64;
    const int col0 = blockIdx.x * 128;
    const int wm = (wave & 1) * 32, wn = (wave >> 1) * 64;

    frag_cd acc[2][4];
#pragma unroll
    for (int mt = 0; mt < 2; mt++)
#pragma unroll
        for (int nt = 0; nt < 4; nt++) acc[mt][nt] = frag_cd{0.f, 0.f, 0.f, 0.f};

    for (int k0 = 0; k0 < D; k0 += BK) {
        __syncthreads();
#pragma unroll
        for (int j = 0; j < 2; j++) {
            const int s = wave * 128 + j * 64 + lane;
            const int r = s >> 3;
            const int c = (s ^ r) & 7;
            gload_lds16(A + (size_t)(row0 + r) * D + k0 + c * 8, &As[(wave * 128 + j * 64) * 8]);
        }
#pragma unroll
        for (int j = 0; j < 4; j++) {
            const int s = wave * 256 + j * 64 + lane;
            const int r = s >> 3;
            const int c = (s ^ r) & 7;
            gload_lds16(Bt + (size_t)(col0 + r) * D + k0 + c * 8, &Bs[(wave * 256 + j * 64) * 8]);
        }
        __syncthreads();

        frag_ab af[2][2], bf[4][2];
#pragma unroll
        for (int mt = 0; mt < 2; mt++) {
            const int row = wm + mt * 16 + r16;
#pragma unroll
            for (int ks = 0; ks < 2; ks++)
                af[mt][ks] = *(const frag_ab*)&As[row * 64 + (((ks * 4 + quad) ^ (row & 7)) * 8)];
        }
#pragma unroll
        for (int nt = 0; nt < 4; nt++) {
            const int row = wn + nt * 16 + r16;
#pragma unroll
            for (int ks = 0; ks < 2; ks++)
                bf[nt][ks] = *(const frag_ab*)&Bs[row * 64 + (((ks * 4 + quad) ^ (row & 7)) * 8)];
        }
#pragma unroll
        for (int mt = 0; mt < 2; mt++)
#pragma unroll
            for (int nt = 0; nt < 4; nt++)
#pragma unroll
                for (int ks = 0; ks < 2; ks++)
                    acc[mt][nt] = __builtin_amdgcn_mfma_f32_16x16x32_bf16(
                        af[mt][ks], bf[nt][ks], acc[mt][nt], 0, 0, 0);
    }

#pragma unroll
    for (int mt = 0; mt < 2; mt++)
#pragma unroll
        for (int nt = 0; nt < 4; nt++) {
            const int col = col0 + wn + nt * 16 + r16;
            const float bv = bias[col];
#pragma unroll
            for (int rg = 0; rg < 4; rg++) {
                const int row = row0 + wm + mt * 16 + quad * 4 + rg;
                Out[(size_t)row * D + col] = acc[mt][nt][rg] + bv;
            }
        }
}

extern "C" void kernel_launch(void* const* d_in, const int* in_sizes, int n_in,
                              void* d_out, int out_size, void* d_ws, size_t ws_size,
                              hipStream_t stream) {
    const float* x  = (const float*)d_in[0];
    const float* Wq = (const float*)d_in[1];
    const float* Wk = (const float*)d_in[2];
    const float* Wv = (const float*)d_in[3];
    const float* Wo = (const float*)d_in[4];
    const float* bo = (const float*)d_in[5];
    float* out = (float*)d_out;

    bf16* xb    = (bf16*)d_ws;                 // [4096][1024]
    bf16* WqkvT = xb    + (size_t)M * D;       // [3072][1024] (WqT|WkT|WvT)
    bf16* WoT   = WqkvT + (size_t)3 * D * D;   // [1024][1024]
    bf16* Qb    = WoT   + (size_t)D * D;       // [B,S,D]
    bf16* Kb    = Qb    + (size_t)M * D;       // [B,S,D]
    bf16* Vt_g  = Kb    + (size_t)M * D;       // [32][64][2048]
    bf16* Ctxb  = Vt_g  + (size_t)M * D;       // [B,S,D]

    cvt_x<<<(M * D) / 1024, 256, 0, stream>>>(x, xb);
    cvt_wT<<<dim3(32, 32, 4), 256, 0, stream>>>(Wq, Wk, Wv, Wo,
                                                WqkvT, WqkvT + (size_t)D * D,
                                                WqkvT + (size_t)2 * D * D, WoT);
    gemm_qkv_all<<<dim3(24, 32), 256, 0, stream>>>(xb, WqkvT, Qb, Kb, Vt_g);
    attn_mfma<<<dim3(B * NH, S / BQ), 256, 0, stream>>>(Qb, Kb, Vt_g, Ctxb);
    gemm_out64<<<dim3(8, 64), 256, 0, stream>>>(Ctxb, WoT, bo, out);
}

// Round 9
// 186.692 us; speedup vs baseline: 27.1240x; 1.0041x over previous
//
#include <hip/hip_runtime.h>
#include <hip/hip_bf16.h>

#define B 2
#define S 2048
#define D 1024
#define NH 16
#define DH 64
#define M (B*S)
#define BQ 128
#define BK 64
#define KSCALE 0.18033688011112042f   // (1/sqrt(64)) * log2(e) — folded into Qb

typedef __hip_bfloat16 bf16;
typedef __attribute__((ext_vector_type(8))) short frag_ab;   // 8 bf16
typedef __attribute__((ext_vector_type(4))) float frag_cd;   // 4 f32
typedef unsigned long long ull;

// async global->LDS, 16B/lane; LDS dest = wave-uniform base + lane*16
__device__ __forceinline__ void gload_lds16(const bf16* g, bf16* l) {
    __builtin_amdgcn_global_load_lds((const __attribute__((address_space(1))) unsigned int*)g,
                                     (__attribute__((address_space(3))) unsigned int*)l,
                                     16, 0, 0);
}

// ---------- convert x fp32 -> bf16
__global__ __launch_bounds__(256) void cvt_x(const float* __restrict__ x, bf16* __restrict__ xb) {
    const int i = (blockIdx.x * 256 + threadIdx.x) * 4;
    const float4 v = *(const float4*)(x + i);
    __align__(8) bf16 t[4] = {__float2bfloat16(v.x), __float2bfloat16(v.y),
                              __float2bfloat16(v.z), __float2bfloat16(v.w)};
    *(ull*)(xb + i) = *(const ull*)t;
}

// ---------- convert + transpose weights: T[n][k] = W[k][n]
__global__ __launch_bounds__(256) void cvt_wT(const float* __restrict__ W0, const float* __restrict__ W1,
                                              const float* __restrict__ W2, const float* __restrict__ W3,
                                              bf16* __restrict__ T0, bf16* __restrict__ T1,
                                              bf16* __restrict__ T2, bf16* __restrict__ T3) {
    const float* src; bf16* dst;
    switch (blockIdx.z) {
        case 0: src = W0; dst = T0; break;
        case 1: src = W1; dst = T1; break;
        case 2: src = W2; dst = T2; break;
        default: src = W3; dst = T3; break;
    }
    __shared__ float t[32][33];
    const int tx = threadIdx.x & 31, ty = threadIdx.x >> 5;
    const int c0 = blockIdx.x * 32, r0 = blockIdx.y * 32;
#pragma unroll
    for (int i = 0; i < 4; i++)
        t[ty + 8 * i][tx] = src[(size_t)(r0 + ty + 8 * i) * D + c0 + tx];
    __syncthreads();
#pragma unroll
    for (int i = 0; i < 4; i++)
        dst[(size_t)(c0 + ty + 8 * i) * D + r0 + tx] = __float2bfloat16(t[tx][ty + 8 * i]);
}

// ---------- fused QKV GEMM: C = xb @ [WqT|WkT|WvT]^T, 128x128 tiles, grid (24,32).
// Q third stored row-major PRE-SCALED by KSCALE; K third row-major; V third
// stored TRANSPOSED per head: Vt[bh][d][s].
__global__ __launch_bounds__(256) void gemm_qkv_all(const bf16* __restrict__ A, const bf16* __restrict__ Bt,
                                                    bf16* __restrict__ Qb, bf16* __restrict__ Kb,
                                                    bf16* __restrict__ Vt_g) {
    __shared__ __align__(16) bf16 As[128 * BK];
    __shared__ __align__(16) bf16 Bs[128 * BK];
    const int tid = threadIdx.x, wave = tid >> 6, lane = tid & 63;
    const int r16 = lane & 15, quad = lane >> 4;
    const int row0 = blockIdx.y * 128;
    const int col0 = blockIdx.x * 128;
    const int wm = (wave & 1) * 64, wn = (wave >> 1) * 64;

    frag_cd acc[4][4];
#pragma unroll
    for (int mt = 0; mt < 4; mt++)
#pragma unroll
        for (int nt = 0; nt < 4; nt++) acc[mt][nt] = frag_cd{0.f, 0.f, 0.f, 0.f};

    for (int k0 = 0; k0 < D; k0 += BK) {
        __syncthreads();
#pragma unroll
        for (int j = 0; j < 4; j++) {
            const int s = wave * 256 + j * 64 + lane;
            const int r = s >> 3;
            const int c = (s ^ r) & 7;
            gload_lds16(A  + (size_t)(row0 + r) * D + k0 + c * 8, &As[(wave * 256 + j * 64) * 8]);
            gload_lds16(Bt + (size_t)(col0 + r) * D + k0 + c * 8, &Bs[(wave * 256 + j * 64) * 8]);
        }
        __syncthreads();

        frag_ab af[4][2], bf[4][2];
#pragma unroll
        for (int mt = 0; mt < 4; mt++) {
            const int row = wm + mt * 16 + r16;
#pragma unroll
            for (int ks = 0; ks < 2; ks++)
                af[mt][ks] = *(const frag_ab*)&As[row * 64 + (((ks * 4 + quad) ^ (row & 7)) * 8)];
        }
#pragma unroll
        for (int nt = 0; nt < 4; nt++) {
            const int row = wn + nt * 16 + r16;
#pragma unroll
            for (int ks = 0; ks < 2; ks++)
                bf[nt][ks] = *(const frag_ab*)&Bs[row * 64 + (((ks * 4 + quad) ^ (row & 7)) * 8)];
        }
#pragma unroll
        for (int mt = 0; mt < 4; mt++)
#pragma unroll
            for (int nt = 0; nt < 4; nt++)
#pragma unroll
                for (int ks = 0; ks < 2; ks++)
                    acc[mt][nt] = __builtin_amdgcn_mfma_f32_16x16x32_bf16(
                        af[mt][ks], bf[nt][ks], acc[mt][nt], 0, 0, 0);
    }

    const int third = col0 >> 10;
    if (third < 2) {
        bf16* Out = (third == 0) ? Qb : Kb;
        const float sc = (third == 0) ? KSCALE : 1.f;
#pragma unroll
        for (int mt = 0; mt < 4; mt++)
#pragma unroll
            for (int nt = 0; nt < 4; nt++) {
                const int cl = (col0 + wn + nt * 16 + r16) & 1023;
#pragma unroll
                for (int rg = 0; rg < 4; rg++) {
                    const int row = row0 + wm + mt * 16 + quad * 4 + rg;
                    Out[(size_t)row * D + cl] = __float2bfloat16(acc[mt][nt][rg] * sc);
                }
            }
    } else {
        const int bb = row0 >> 11;
        const int sb0 = (row0 & 2047) + wm;
#pragma unroll
        for (int mt = 0; mt < 4; mt++)
#pragma unroll
            for (int nt = 0; nt < 4; nt++) {
                const int c  = (col0 + wn + nt * 16 + r16) - 2048;
                const int hh = c >> 6, dl = c & 63;
                const int sb = sb0 + mt * 16 + quad * 4;
                __align__(8) bf16 t4[4];
#pragma unroll
                for (int rg = 0; rg < 4; rg++) t4[rg] = __float2bfloat16(acc[mt][nt][rg]);
                *(ull*)(Vt_g + (((size_t)bb * 16 + hh) * 64 + dl) * S + sb) = *(const ull*)t4;
            }
    }
}

// ---------- Flash attention, S^T + transposed-O accumulation, PAIR-UNROLLED
// K-loop: one barrier + one paired prefetch per 128 keys.
// Q (pre-scaled),K bf16 [B,S,D]; Vg = Vt[bh][d][s]; Ctx bf16 [B,S,D].
__global__ __launch_bounds__(256) void attn_mfma(const bf16* __restrict__ Q,
                                                 const bf16* __restrict__ K,
                                                 const bf16* __restrict__ Vg,
                                                 bf16* __restrict__ Ctx) {
    __shared__ __align__(16) bf16 Ks[2][2][BK * DH];   // [buf][sub] 8 KB each = 32 KB
    __shared__ __align__(16) bf16 Vt[2][2][BK * DH];   // 32 KB, rows=dim cols=key
    __shared__ __align__(16) bf16 Qs[BQ * DH];         // 16 KB staging; overlaid by Ps
    bf16* Ps = Qs;   // [128][64], granule(4-elem)-XOR swizzled; rows wave-private

    const int tid = threadIdx.x, wave = tid >> 6, lane = tid & 63;
    const int r16 = lane & 15, quad = lane >> 4;
    const int bh = blockIdx.x, jy = blockIdx.y;
    const int qt = (jy < 8) ? jy : 23 - jy;   // pair-balanced: co-resident pair sums const
    const int b = bh >> 4, h = bh & 15;
    const size_t base  = (size_t)b * S * D + (size_t)h * DH;
    const size_t vbase = (size_t)bh * DH * S;
    const int q0 = qt * BQ;
    const int qwave = q0 + wave * 32;
    const int npair = qt + 1;                 // (2qt+2) 64-key tiles = qt+1 pairs

    // ---- prologue: async-stage Q tile and K/V pair 0 (buf 0)
#pragma unroll
    for (int j = 0; j < 4; j++) {
        const int s = wave * 256 + j * 64 + lane;
        const int r = s >> 3;
        const int c = (s ^ r) & 7;
        gload_lds16(Q + base + (size_t)(q0 + r) * D + c * 8, &Qs[(wave * 256 + j * 64) * 8]);
    }
#pragma unroll
    for (int j = 0; j < 2; j++) {
        const int s = wave * 128 + j * 64 + lane;
        const int r = s >> 3;
        const int c = (s ^ r) & 7;
#pragma unroll
        for (int sub = 0; sub < 2; sub++) {
            gload_lds16(K  + base  + (size_t)(sub * 64 + r) * D + c * 8,
                        &Ks[0][sub][(wave * 128 + j * 64) * 8]);
            gload_lds16(Vg + vbase + (size_t)r * S + sub * 64 + c * 8,
                        &Vt[0][sub][(wave * 128 + j * 64) * 8]);
        }
    }
    __syncthreads();

    // hoist Q B-frags (registers from here on; Qs LDS free to reuse as Ps)
    frag_ab qf[2][2];
#pragma unroll
    for (int nq = 0; nq < 2; nq++)
#pragma unroll
        for (int ks = 0; ks < 2; ks++) {
            const int row = wave * 32 + nq * 16 + r16;
            qf[nq][ks] = *(const frag_ab*)&Qs[row * 64 + (((ks * 4 + quad) ^ (row & 7)) * 8)];
        }

    float mrun[2] = {-1e30f, -1e30f}, lrun[2] = {0.f, 0.f};
    frag_cd Oacc[2][4];   // O^T tile: row=d(quad*4+rg), col=q(r16)
#pragma unroll
    for (int mq = 0; mq < 2; mq++)
#pragma unroll
        for (int nd = 0; nd < 4; nd++) Oacc[mq][nd] = frag_cd{0.f, 0.f, 0.f, 0.f};

    for (int p = 0; p < npair; p++) {
        const int cur = p & 1;

        // ---- prefetch next K/V pair into alternate buffers (hidden under 2 sub-computes)
        if (p + 1 < npair) {
            const int kn = (2 * p + 2) * BK;
#pragma unroll
            for (int j = 0; j < 2; j++) {
                const int s = wave * 128 + j * 64 + lane;
                const int r = s >> 3;
                const int c = (s ^ r) & 7;
#pragma unroll
                for (int sub = 0; sub < 2; sub++) {
                    gload_lds16(K  + base  + (size_t)(kn + sub * 64 + r) * D + c * 8,
                                &Ks[cur ^ 1][sub][(wave * 128 + j * 64) * 8]);
                    gload_lds16(Vg + vbase + (size_t)r * S + kn + sub * 64 + c * 8,
                                &Vt[cur ^ 1][sub][(wave * 128 + j * 64) * 8]);
                }
            }
        }

#pragma unroll
        for (int sub = 0; sub < 2; sub++) {
            const int k0 = (2 * p + sub) * BK;
            if (k0 > qwave + 31) continue;   // fully-masked sub-tile for this wave

            frag_ab ka[4][2];
#pragma unroll
            for (int mk = 0; mk < 4; mk++) {
                const int row = mk * 16 + r16;
#pragma unroll
                for (int ks = 0; ks < 2; ks++)
                    ka[mk][ks] = *(const frag_ab*)&Ks[cur][sub][row * 64 + (((ks * 4 + quad) ^ (row & 7)) * 8)];
            }
            const bool domask = (k0 + BK - 1 > qwave);

#pragma unroll
            for (int nq = 0; nq < 2; nq++) {
                frag_cd Sc[4];
#pragma unroll
                for (int mk = 0; mk < 4; mk++) {
                    Sc[mk] = frag_cd{0.f, 0.f, 0.f, 0.f};
#pragma unroll
                    for (int ks = 0; ks < 2; ks++)
                        Sc[mk] = __builtin_amdgcn_mfma_f32_16x16x32_bf16(
                            ka[mk][ks], qf[nq][ks], Sc[mk], 0, 0, 0);
                }
                // S^T C-layout: col(r16)=q, row(quad*4+rg in mk-tile)=key.
                // Scores already in log2-domain (KSCALE folded into Q).
                const int qg = q0 + wave * 32 + nq * 16 + r16;
                float mx = -1e30f;
#pragma unroll
                for (int mk = 0; mk < 4; mk++)
#pragma unroll
                    for (int rg = 0; rg < 4; rg++) {
                        float sv = Sc[mk][rg];
                        if (domask) {
                            const int keyg = k0 + mk * 16 + quad * 4 + rg;
                            sv = (keyg <= qg) ? sv : -1e30f;
                        }
                        Sc[mk][rg] = sv;
                        mx = fmaxf(mx, sv);
                    }
                mx = fmaxf(mx, __shfl_xor(mx, 16, 64));
                mx = fmaxf(mx, __shfl_xor(mx, 32, 64));
                const float mnew  = fmaxf(mrun[nq], mx);
                const float alpha = __builtin_amdgcn_exp2f(mrun[nq] - mnew);
                mrun[nq] = mnew;
                float rs = 0.f;
#pragma unroll
                for (int mk = 0; mk < 4; mk++)
#pragma unroll
                    for (int rg = 0; rg < 4; rg++) {
                        const float pv = __builtin_amdgcn_exp2f(Sc[mk][rg] - mnew);
                        Sc[mk][rg] = pv;
                        rs += pv;
                    }
                rs += __shfl_xor(rs, 16, 64);
                rs += __shfl_xor(rs, 32, 64);
                lrun[nq] = lrun[nq] * alpha + rs;

                // packed P write: 4 consecutive keys/lane, granule-XOR swizzle (b64 floor)
                const int qrow = wave * 32 + nq * 16 + r16;
#pragma unroll
                for (int mk = 0; mk < 4; mk++) {
                    __align__(8) bf16 t4[4];
#pragma unroll
                    for (int rg = 0; rg < 4; rg++) t4[rg] = __float2bfloat16(Sc[mk][rg]);
                    const int g = (mk * 4 + quad) ^ r16;
                    *(ull*)&Ps[qrow * 64 + g * 4] = *(const ull*)t4;
                }
                // rescale O^T: col=q=r16 matches alpha's index — direct multiply
#pragma unroll
                for (int nd = 0; nd < 4; nd++)
#pragma unroll
                    for (int rg = 0; rg < 4; rg++) Oacc[nq][nd][rg] *= alpha;
            }
            // no barrier: Ps rows wave-private; per-wave LDS ops are in-order

            // PV (transposed): O^T[d][q] += Vt(d rows) x P(q rows)
            frag_ab pa[2][2], vb[4][2];
#pragma unroll
            for (int mq = 0; mq < 2; mq++) {
                const int row = wave * 32 + mq * 16 + r16;
#pragma unroll
                for (int ks = 0; ks < 2; ks++) {
                    const int gb = ks * 8 + quad * 2;
                    union { ull u[2]; frag_ab f; } t;
                    t.u[0] = *(const ull*)&Ps[row * 64 + ((gb    ) ^ r16) * 4];
                    t.u[1] = *(const ull*)&Ps[row * 64 + ((gb + 1) ^ r16) * 4];
                    pa[mq][ks] = t.f;
                }
            }
#pragma unroll
            for (int nd = 0; nd < 4; nd++) {
                const int row = nd * 16 + r16;
#pragma unroll
                for (int ks = 0; ks < 2; ks++)
                    vb[nd][ks] = *(const frag_ab*)&Vt[cur][sub][row * 64 + (((ks * 4 + quad) ^ (row & 7)) * 8)];
            }
#pragma unroll
            for (int mq = 0; mq < 2; mq++)
#pragma unroll
                for (int nd = 0; nd < 4; nd++)
#pragma unroll
                    for (int ks = 0; ks < 2; ks++)
                        Oacc[mq][nd] = __builtin_amdgcn_mfma_f32_16x16x32_bf16(
                            vb[nd][ks], pa[mq][ks], Oacc[mq][nd], 0, 0, 0);
        }

        __syncthreads();   // joins: pair prefetch complete + all waves done with cur bufs
    }

    // epilogue: Ctx[q][d] = O^T[d][q] / l — lane holds 4 consecutive d -> packed b64
#pragma unroll
    for (int mq = 0; mq < 2; mq++) {
        const float invl = 1.f / lrun[mq];
        const int qg = q0 + wave * 32 + mq * 16 + r16;
#pragma unroll
        for (int nd = 0; nd < 4; nd++) {
            __align__(8) bf16 t4[4];
#pragma unroll
            for (int rg = 0; rg < 4; rg++)
                t4[rg] = __float2bfloat16(Oacc[mq][nd][rg] * invl);
            *(ull*)(Ctx + base + (size_t)qg * D + nd * 16 + quad * 4) = *(const ull*)t4;
        }
    }
}

// ---------- output projection, 64x128 tiles (512 blocks), fp32 out + bias
__global__ __launch_bounds__(256) void gemm_out64(const bf16* __restrict__ A, const bf16* __restrict__ Bt,
                                                  const float* __restrict__ bias, float* __restrict__ Out) {
    __shared__ __align__(16) bf16 As[64 * BK];
    __shared__ __align__(16) bf16 Bs[128 * BK];
    const int tid = threadIdx.x, wave = tid >> 6, lane = tid & 63;
    const int r16 = lane & 15, quad = lane >> 4;
    const int row0 = blockIdx.y * 64;
    const int col0 = blockIdx.x * 128;
    const int wm = (wave & 1) * 32, wn = (wave >> 1) * 64;

    frag_cd acc[2][4];
#pragma unroll
    for (int mt = 0; mt < 2; mt++)
#pragma unroll
        for (int nt = 0; nt < 4; nt++) acc[mt][nt] = frag_cd{0.f, 0.f, 0.f, 0.f};

    for (int k0 = 0; k0 < D; k0 += BK) {
        __syncthreads();
#pragma unroll
        for (int j = 0; j < 2; j++) {
            const int s = wave * 128 + j * 64 + lane;
            const int r = s >> 3;
            const int c = (s ^ r) & 7;
            gload_lds16(A + (size_t)(row0 + r) * D + k0 + c * 8, &As[(wave * 128 + j * 64) * 8]);
        }
#pragma unroll
        for (int j = 0; j < 4; j++) {
            const int s = wave * 256 + j * 64 + lane;
            const int r = s >> 3;
            const int c = (s ^ r) & 7;
            gload_lds16(Bt + (size_t)(col0 + r) * D + k0 + c * 8, &Bs[(wave * 256 + j * 64) * 8]);
        }
        __syncthreads();

        frag_ab af[2][2], bf[4][2];
#pragma unroll
        for (int mt = 0; mt < 2; mt++) {
            const int row = wm + mt * 16 + r16;
#pragma unroll
            for (int ks = 0; ks < 2; ks++)
                af[mt][ks] = *(const frag_ab*)&As[row * 64 + (((ks * 4 + quad) ^ (row & 7)) * 8)];
        }
#pragma unroll
        for (int nt = 0; nt < 4; nt++) {
            const int row = wn + nt * 16 + r16;
#pragma unroll
            for (int ks = 0; ks < 2; ks++)
                bf[nt][ks] = *(const frag_ab*)&Bs[row * 64 + (((ks * 4 + quad) ^ (row & 7)) * 8)];
        }
#pragma unroll
        for (int mt = 0; mt < 2; mt++)
#pragma unroll
            for (int nt = 0; nt < 4; nt++)
#pragma unroll
                for (int ks = 0; ks < 2; ks++)
                    acc[mt][nt] = __builtin_amdgcn_mfma_f32_16x16x32_bf16(
                        af[mt][ks], bf[nt][ks], acc[mt][nt], 0, 0, 0);
    }

#pragma unroll
    for (int mt = 0; mt < 2; mt++)
#pragma unroll
        for (int nt = 0; nt < 4; nt++) {
            const int col = col0 + wn + nt * 16 + r16;
            const float bv = bias[col];
#pragma unroll
            for (int rg = 0; rg < 4; rg++) {
                const int row = row0 + wm + mt * 16 + quad * 4 + rg;
                Out[(size_t)row * D + col] = acc[mt][nt][rg] + bv;
            }
        }
}

extern "C" void kernel_launch(void* const* d_in, const int* in_sizes, int n_in,
                              void* d_out, int out_size, void* d_ws, size_t ws_size,
                              hipStream_t stream) {
    const float* x  = (const float*)d_in[0];
    const float* Wq = (const float*)d_in[1];
    const float* Wk = (const float*)d_in[2];
    const float* Wv = (const float*)d_in[3];
    const float* Wo = (const float*)d_in[4];
    const float* bo = (const float*)d_in[5];
    float* out = (float*)d_out;

    bf16* xb    = (bf16*)d_ws;                 // [4096][1024]
    bf16* WqkvT = xb    + (size_t)M * D;       // [3072][1024] (WqT|WkT|WvT)
    bf16* WoT   = WqkvT + (size_t)3 * D * D;   // [1024][1024]
    bf16* Qb    = WoT   + (size_t)D * D;       // [B,S,D] (pre-scaled by KSCALE)
    bf16* Kb    = Qb    + (size_t)M * D;       // [B,S,D]
    bf16* Vt_g  = Kb    + (size_t)M * D;       // [32][64][2048]
    bf16* Ctxb  = Vt_g  + (size_t)M * D;       // [B,S,D]

    cvt_x<<<(M * D) / 1024, 256, 0, stream>>>(x, xb);
    cvt_wT<<<dim3(32, 32, 4), 256, 0, stream>>>(Wq, Wk, Wv, Wo,
                                                WqkvT, WqkvT + (size_t)D * D,
                                                WqkvT + (size_t)2 * D * D, WoT);
    gemm_qkv_all<<<dim3(24, 32), 256, 0, stream>>>(xb, WqkvT, Qb, Kb, Vt_g);
    attn_mfma<<<dim3(B * NH, S / BQ), 256, 0, stream>>>(Qb, Kb, Vt_g, Ctxb);
    gemm_out64<<<dim3(8, 64), 256, 0, stream>>>(Ctxb, WoT, bo, out);
}